// Round 4
// baseline (481.891 us; speedup 1.0000x reference)
//
#include <hip/hip_runtime.h>
#include <hip/hip_bf16.h>
#include <hip/hip_fp16.h>
#include <math.h>

#define DEV_INLINE __device__ __forceinline__

typedef __attribute__((ext_vector_type(8))) short short8;
typedef __attribute__((ext_vector_type(8))) unsigned short ushort8v;
typedef __attribute__((ext_vector_type(4))) float f32x4;

constexpr int H = 128, W = 128, C = 128, B = 4;
constexpr int KK = 9;
constexpr int KT2 = 1184;         // 37 chunks * 32

DEV_INLINE unsigned short f2bf(float f) {
  union { float f; unsigned u; } v; v.f = f;
  unsigned r = v.u + 0x7FFFu + ((v.u >> 16) & 1u);   // RNE
  return (unsigned short)(r >> 16);
}
DEV_INLINE float ubits(unsigned u) {
  union { unsigned u; float f; } v; v.u = u; return v.f;
}
DEV_INLINE unsigned pack2bf(float a, float b) {
  float2 t; t.x = a; t.y = b;
  __hip_bfloat162 h = __float22bfloat162_rn(t);
  union { __hip_bfloat162 h; unsigned u; } c; c.h = h;
  return c.u;
}
DEV_INLINE unsigned f2h2(float a, float b) {
  __half2 h = __floats2half2_rn(a, b);
  union { __half2 h; unsigned u; } c; c.h = h;
  return c.u;
}
DEV_INLINE float2 h2f2(unsigned u) {
  union { unsigned u; __half2 h; } c; c.u = u;
  return __half22float2(c.h);
}
// async global->LDS, 16B per lane (wave-uniform LDS base + lane*16)
DEV_INLINE void gload_lds16(const unsigned short* g, unsigned short* l) {
  __builtin_amdgcn_global_load_lds(
      (const __attribute__((address_space(1))) unsigned*)g,
      (__attribute__((address_space(3))) unsigned*)l, 16, 0, 0);
}

// K-SPLIT fused deform layer (round 4). Rounds 0-3: four different schedules
// all ~117-137 us, every pipe <30% busy => TLP-starved: 4096 waves total
// (grid 1024), 16 waves/CU, regs ~100/wave. This version splits each spatial
// block into TWO half-K blocks (khalf 0: taps 0-4, khalf 1: taps 5-8) ->
// grid 2048, LDS 20.2 KB/block, so 5+ blocks/CU can be resident.
//   Phase 1: offset conv with PERMUTED output channels: half h computes only
//            its taps' (oy,ox,m) = 15/12 cols -> NT=1 (one MFMA/chunk; global
//            MFMA work unchanged, only the src stream is duplicated).
//   Phase 2: bilinear table -> sTab LDS [ntap][64] x 3 dwords
//            {rowpair id, fp16 w01, fp16 w23}. BN-column B-frag (layer 1)
//            built per half from sTab (splits linearly across halves).
//   Phase 3: deform GEMM over this half's 20/16 chunks (+BN col), counted-
//            vmcnt pipeline as round 3 (stage ch+1 via global_load_lds ->
//            blend -> 8 MFMA -> gathers ch+2 -> vmcnt(4)+s_barrier).
//   Epilogue: store raw fp32 NHWC partial (combine kernels finish PReLU /
//            BN2+residual).
template<int LAYER>
__global__ __launch_bounds__(256, 5)
void fusedL(const unsigned short* __restrict__ src,     // NHWC bf16
            const unsigned short* __restrict__ wOM,     // [37][2][64][8]
            const unsigned short* __restrict__ wS,      // [37][8][64][8]
            const float* __restrict__ bias,             // [2][16]
            float* __restrict__ pOut0,                  // fp32 NHWC partial
            float* __restrict__ pOut1)
{
  constexpr bool BN = (LAYER == 1);
  __shared__ __attribute__((aligned(16))) char smem[20224];
  float* sOff = (float*)smem;                            // [64][17] = 4352 B
  unsigned short* aBuf0 = (unsigned short*)smem;         // 8 KB (overlays sOff)
  unsigned short* aBuf1 = (unsigned short*)(smem + 8192);
  unsigned* sTab = (unsigned*)(smem + 16384);            // [5][64] x 3 dwords

  const int tid  = threadIdx.x;
  const int lane = tid & 63;
  const int m16  = lane & 15;
  const int q    = lane >> 4;
  const int wv   = tid >> 6;

  const int raw   = blockIdx.x;               // 2048 blocks
  const int xcd   = raw & 7;
  const int khalf = (raw >> 3) & 1;           // K-half (same XCD as sibling)
  const int slot  = raw >> 4;                 // [0,128)
  const int b     = xcd >> 1;
  const int hy    = ((xcd & 1) << 6) | (slot >> 1);
  const int hx0   = (slot & 1) << 6;          // 64-wide segment
  const unsigned short* __restrict__ srcB = src + ((size_t)b << 14) * C;

  const int t0   = khalf ? 5 : 0;             // first tap of this half
  const int ntap = khalf ? 4 : 5;
  const int nch  = ntap << 2;                 // 16 / 20 chunks
  const int ch0g = t0 << 2;                   // global chunk base
  const int nom  = khalf ? 12 : 15;           // offset-conv cols this half

  const int pos = (wv << 4) + m16;            // block-local position
  const int hx  = hx0 + pos;
  const int cbq = q << 3;

  // ================= Phase 1: offset conv (NT=1, rolled, prefetched) =======
  f32x4 accO = (f32x4){0.f, 0.f, 0.f, 0.f};

  ushort8v pv;
  bool pvok;
  {
    const int iy = hy - 1, ix = hx - 1;       // ch=0: tap 0 (ky=0,kx=0), cg=0
    pvok = ((unsigned)iy < (unsigned)H) && ((unsigned)ix < (unsigned)W);
    const int rb = pvok ? (iy * W + ix) : 0;
    pv = *(const ushort8v*)(srcB + ((size_t)rb * C + cbq));
  }
  short8 pa0 = *(const short8*)(wOM + ((size_t)(khalf * 64 + lane)) * 8);

  #pragma unroll 1
  for (int ch = 0; ch < 36; ++ch) {
    const short8 a0 = pa0;
    if (ch + 1 < 36) {                         // weight prefetch (L1/L2-hot)
      pa0 = *(const short8*)(wOM + ((size_t)((ch + 1) * 128 + khalf * 64 + lane)) * 8);
    }
    ushort8v nv = pv;
    bool nok = false;
    if (ch + 1 < 36) {                         // source prefetch
      const int tapn = (ch + 1) >> 2, cgn = (ch + 1) & 3;
      const int ky = tapn / 3, kx = tapn - 3 * (tapn / 3);
      const int iy = hy + ky - 1;
      const int ix = hx + kx - 1;
      nok = ((unsigned)iy < (unsigned)H) && ((unsigned)ix < (unsigned)W);
      const int rb = nok ? (iy * W + ix) : 0;
      nv = *(const ushort8v*)(srcB + ((size_t)rb * C + (cgn << 5) + cbq));
    }
    union { ushort8v v; unsigned u[4]; short8 s; } bfr;
    bfr.v = pv;
    if (!pvok) { bfr.u[0] = 0; bfr.u[1] = 0; bfr.u[2] = 0; bfr.u[3] = 0; }
    accO = __builtin_amdgcn_mfma_f32_16x16x32_bf16(a0, bfr.s, accO, 0, 0, 0);
    pv = nv; pvok = nok;
  }
  if constexpr (BN) {   // validity column chunk
    union { unsigned u[4]; short8 s; } bfr;
    float sv[8];
    #pragma unroll
    for (int j = 0; j < 8; ++j) {
      const int kj = cbq + j;
      float s = 0.f;
      if (kj < KK) {
        const int ky = kj / 3, kx = kj - 3 * (kj / 3);
        const int iy = hy + ky - 1, ix = hx + kx - 1;
        s = (((unsigned)iy < (unsigned)H) && ((unsigned)ix < (unsigned)W)) ? 1.f : 0.f;
      }
      sv[j] = s;
    }
    #pragma unroll
    for (int t = 0; t < 4; ++t) bfr.u[t] = pack2bf(sv[2 * t], sv[2 * t + 1]);
    const short8 a36 = *(const short8*)(wOM + ((size_t)(36 * 128 + khalf * 64 + lane)) * 8);
    accO = __builtin_amdgcn_mfma_f32_16x16x32_bf16(a36, bfr.s, accO, 0, 0, 0);
  }
  // epilogue -> sOff[pos][o], o = q*4+rg local col (tap-major: o = 3*tloc+comp)
  #pragma unroll
  for (int rg = 0; rg < 4; ++rg) {
    const int o = (q << 2) + rg;
    if (o < nom) {
      float vv = accO[rg] + bias[khalf * 16 + o];
      if (o - 3 * (o / 3) == 2) vv = 2.f / (1.f + expf(-vv));   // mask comp
      sOff[pos * 17 + o] = vv;
    }
  }
  __syncthreads();

  // ================= Phase 2: bilinear table -> sTab LDS ===================
  {
    const float* myOff = sOff + pos * 17;
    #pragma unroll 1
    for (int tloc = 0; tloc < ntap; ++tloc) {
      const int tap = t0 + tloc;
      const int ky = tap / 3, kx = tap - 3 * (tap / 3);
      const float oy = myOff[tloc * 3 + 0];
      const float ox = myOff[tloc * 3 + 1];
      const float mv = myOff[tloc * 3 + 2];
      const float py = (float)(hy - 1 + ky) + oy;
      const float px = (float)(hx - 1 + kx) + ox;
      const float fy = floorf(py), fx = floorf(px);
      const float ay = py - fy, ax = px - fx;
      const int y0 = (int)fy, x0 = (int)fx;
      const int y1 = y0 + 1, x1 = x0 + 1;
      const float wyt = (1.f - ay) * (((unsigned)y0 < (unsigned)H) ? 1.f : 0.f);
      const float wyb = ay * (((unsigned)y1 < (unsigned)H) ? 1.f : 0.f);
      const int y0c = min(max(y0, 0), H - 1), y1c = min(max(y1, 0), H - 1);
      const int bx  = min(max(x0, 0), W - 2);
      float wA = 0.f, wB = 0.f;
      if (x0 == bx)          { wA = 1.f - ax; wB = ax; }
      else if (x1 == bx)     { wA = ax; }
      else if (x0 == bx + 1) { wB = 1.f - ax; }
      if (q == 0) {   // one writer per pos (all q computed identical values)
        const int tb = (tloc * 64 + pos) * 3;
        sTab[tb + 0] = (unsigned)(y0c * W + bx) | ((unsigned)(y1c * W + bx) << 16);
        sTab[tb + 1] = f2h2(mv * wyt * wA, mv * wyt * wB);
        sTab[tb + 2] = f2h2(mv * wyb * wA, mv * wyb * wB);
      }
    }
  }
  __syncthreads();   // sOff dead + sTab visible; aBuf0 may now be written

  // BN-column B fragment for THIS half (kj in [t0, t0+ntap)), from sTab
  unsigned bnB0 = 0, bnB1 = 0, bnB2 = 0, bnB3 = 0;
  if constexpr (BN) {
    float sv[8];
    #pragma unroll
    for (int j = 0; j < 8; ++j) {
      int tl = -1;
      if (khalf == 0) { if (q == 0 && j < 5) tl = j; }
      else            { if (q == 0 && j >= 5) tl = j - 5;
                        else if (q == 1 && j == 0) tl = 3; }
      float s = 0.f;
      if (tl >= 0) {
        const int tb = (tl * 64 + pos) * 3;
        const float2 a = h2f2(sTab[tb + 1]);
        const float2 c = h2f2(sTab[tb + 2]);
        s = a.x + a.y + c.x + c.y;
      }
      sv[j] = s;
    }
    bnB0 = pack2bf(sv[0], sv[1]); bnB1 = pack2bf(sv[2], sv[3]);
    bnB2 = pack2bf(sv[4], sv[5]); bnB3 = pack2bf(sv[6], sv[7]);
  }

  // ================= Phase 3: deform GEMM (rolled, counted-vmcnt) ==========
  f32x4 acc[8];
  #pragma unroll
  for (int i = 0; i < 8; ++i) acc[i] = (f32x4){0.f, 0.f, 0.f, 0.f};

  ushort8v gTL[2], gTR[2], gBL[2], gBR[2];   // depth-2 gather pipeline

  // prologue: stage first chunk, read tap-0 table entry, gathers chunks 0,1
  {
    unsigned short* dst0 = aBuf0 + (wv << 9);        // wave-uniform base
    const size_t gb = (size_t)ch0g * 4096;
    gload_lds16(wS + gb + (size_t)tid * 8, dst0);
    gload_lds16(wS + gb + (size_t)(256 + tid) * 8, dst0 + 2048);
  }
  asm volatile("" ::: "memory");   // staging issued before gathers (vmcnt order)
  unsigned tIdC, wPk01, wPk23;
  {
    const int tb = pos * 3;
    tIdC = sTab[tb]; wPk01 = sTab[tb + 1]; wPk23 = sTab[tb + 2];
  }
  #pragma unroll
  for (int pc = 0; pc < 2; ++pc) {
    const int cbase = (pc << 5) + cbq;
    const unsigned short* pT  = srcB + ((size_t)(tIdC & 0xFFFFu) * C + cbase);
    const unsigned short* pBt = srcB + ((size_t)(tIdC >> 16) * C + cbase);
    gTL[pc] = *(const ushort8v*)(pT);
    gTR[pc] = *(const ushort8v*)(pT + C);
    gBL[pc] = *(const ushort8v*)(pBt);
    gBR[pc] = *(const ushort8v*)(pBt + C);
  }
  asm volatile("s_waitcnt vmcnt(8)" ::: "memory");   // staging retired
  __builtin_amdgcn_s_barrier();
  __builtin_amdgcn_sched_barrier(0);

  unsigned tIdN = tIdC, nPk01 = wPk01, nPk23 = wPk23;
  #pragma unroll 1
  for (int tloc = 0; tloc < ntap; ++tloc) {
    #pragma unroll
    for (int cg = 0; cg < 4; ++cg) {
      const int lch = (tloc << 2) + cg;
      const bool more = (lch + 1) < (nch + (BN ? 1 : 0));
      // ---- stage next chunk (async, other buffer) ----
      if (more) {
        unsigned short* wd = ((cg + 1) & 1) ? aBuf1 : aBuf0;
        unsigned short* dst = wd + (wv << 9);
        const int gch = (lch + 1 < nch) ? (ch0g + lch + 1) : 36;
        const size_t gb = (size_t)gch * 4096;
        gload_lds16(wS + gb + (size_t)tid * 8, dst);
        gload_lds16(wS + gb + (size_t)(256 + tid) * 8, dst + 2048);
      }
      asm volatile("" ::: "memory");   // pin staging before this iter's gathers

      // ---- prefetch next tap's table entry (used for cg>=2 gathers) ----
      if (cg == 2 && tloc + 1 < ntap) {
        const int tb = ((tloc + 1) * 64 + pos) * 3;
        tIdN = sTab[tb]; nPk01 = sTab[tb + 1]; nPk23 = sTab[tb + 2];
      }

      // ---- blend current gathers -> B fragment ----
      const float2 w01 = h2f2(wPk01);
      const float2 w23 = h2f2(wPk23);
      union { ushort8v v; unsigned u[4]; } cT, cR, cB, cQ;
      cT.v = gTL[cg & 1]; cR.v = gTR[cg & 1];
      cB.v = gBL[cg & 1]; cQ.v = gBR[cg & 1];
      union { unsigned u[4]; short8 s; } bfr;
      #pragma unroll
      for (int t = 0; t < 4; ++t) {
        const unsigned uT = cT.u[t], uR = cR.u[t], uB = cB.u[t], uQ = cQ.u[t];
        const float sv0 = w01.x * ubits(uT << 16) + w01.y * ubits(uR << 16)
                        + w23.x * ubits(uB << 16) + w23.y * ubits(uQ << 16);
        const float sv1 = w01.x * ubits(uT & 0xFFFF0000u) + w01.y * ubits(uR & 0xFFFF0000u)
                        + w23.x * ubits(uB & 0xFFFF0000u) + w23.y * ubits(uQ & 0xFFFF0000u);
        bfr.u[t] = pack2bf(sv0, sv1);
      }

      // ---- A-fragments from LDS + MFMA ----
      const unsigned short* rbuf = (cg & 1) ? aBuf1 : aBuf0;
      #pragma unroll
      for (int ot = 0; ot < 8; ++ot) {
        const short8 afr = *(const short8*)(rbuf + ((size_t)(ot * 64 + lane)) * 8);
        acc[ot] = __builtin_amdgcn_mfma_f32_16x16x32_bf16(afr, bfr.s, acc[ot], 0, 0, 0);
      }

      // ---- issue gathers for chunk lch+2 (consumed 2 chunks later) ----
      if (lch + 2 < nch) {
        const unsigned idp = (cg < 2) ? tIdC : tIdN;
        const int cbase = (((cg + 2) & 3) << 5) + cbq;
        const unsigned short* pT  = srcB + ((size_t)(idp & 0xFFFFu) * C + cbase);
        const unsigned short* pBt = srcB + ((size_t)(idp >> 16) * C + cbase);
        gTL[cg & 1] = *(const ushort8v*)(pT);
        gTR[cg & 1] = *(const ushort8v*)(pT + C);
        gBL[cg & 1] = *(const ushort8v*)(pBt);
        gBR[cg & 1] = *(const ushort8v*)(pBt + C);
      }

      // ---- counted wait: staging retired, newest gathers stay in flight ----
      if (more) {
        asm volatile("s_waitcnt vmcnt(4)" ::: "memory");
        __builtin_amdgcn_s_barrier();
        __builtin_amdgcn_sched_barrier(0);
      }
    }
    tIdC = tIdN; wPk01 = nPk01; wPk23 = nPk23;   // rotate to next tap
  }

  if constexpr (BN) {   // BN-shift column chunk (this half's taps only)
    asm volatile("s_waitcnt vmcnt(0)" ::: "memory");
    __builtin_amdgcn_s_barrier();
    union { unsigned u[4]; short8 s; } bfr;
    bfr.u[0] = bnB0; bfr.u[1] = bnB1; bfr.u[2] = bnB2; bfr.u[3] = bnB3;
    #pragma unroll
    for (int ot = 0; ot < 8; ++ot) {
      const short8 afr = *(const short8*)(aBuf0 + ((size_t)(ot * 64 + lane)) * 8);
      acc[ot] = __builtin_amdgcn_mfma_f32_16x16x32_bf16(afr, bfr.s, acc[ot], 0, 0, 0);
    }
  }

  // ---- epilogue: raw fp32 NHWC partial ----
  float* po = khalf ? pOut1 : pOut0;
  const size_t pbase = ((size_t)((b << 14) + hy * W + hx)) * 128;
  #pragma unroll
  for (int ot = 0; ot < 8; ++ot) {
    *(f32x4*)(po + pbase + (ot << 4) + (q << 2)) = acc[ot];
  }
}

// combine layer 1: sum partials + PReLU -> NHWC bf16
__global__ __launch_bounds__(256, 4)
void combL1(const float* __restrict__ p0, const float* __restrict__ p1,
            const float* __restrict__ alpha, unsigned short* __restrict__ outh)
{
  const size_t i4 = ((size_t)blockIdx.x * 256 + threadIdx.x) * 4;
  const float4 a = *(const float4*)(p0 + i4);
  const float4 c = *(const float4*)(p1 + i4);
  const float4 al = *(const float4*)(alpha + (i4 & 127));
  const float v0 = a.x + c.x, v1 = a.y + c.y, v2 = a.z + c.z, v3 = a.w + c.w;
  uint2 st;
  st.x = pack2bf(v0 > 0.f ? v0 : al.x * v0, v1 > 0.f ? v1 : al.y * v1);
  st.y = pack2bf(v2 > 0.f ? v2 : al.z * v2, v3 > 0.f ? v3 : al.w * v3);
  *(uint2*)(outh + i4) = st;
}

// combine layer 2: sum partials (NHWC fp32) + BN2 + residual -> NCHW fp32
__global__ __launch_bounds__(256, 4)
void combL2(const float* __restrict__ p0, const float* __restrict__ p1,
            const float* __restrict__ g, const float* __restrict__ bb,
            const float* __restrict__ m, const float* __restrict__ v,
            const float* __restrict__ resid, float* __restrict__ out)
{
  __shared__ float tile[64 * 129];
  const int b    = blockIdx.y;
  const int posb = blockIdx.x * 64;
  const int tid  = threadIdx.x;
  {
    const int pl = tid >> 2, cq = tid & 3;
    const size_t base = ((size_t)(b * 16384 + posb + pl)) * 128 + cq * 32;
    #pragma unroll
    for (int j = 0; j < 8; ++j) {
      const float4 a = *(const float4*)(p0 + base + j * 4);
      const float4 c = *(const float4*)(p1 + base + j * 4);
      float* t = tile + pl * 129 + cq * 32 + j * 4;
      t[0] = a.x + c.x; t[1] = a.y + c.y; t[2] = a.z + c.z; t[3] = a.w + c.w;
    }
  }
  __syncthreads();
  {
    const int cg = tid >> 6, pl = tid & 63;
    #pragma unroll 1
    for (int j = 0; j < 32; ++j) {
      const int ch = cg * 32 + j;
      const float s  = g[ch] * rsqrtf(v[ch] + 1e-5f);
      const float sh = bb[ch] - m[ch] * s;
      const size_t oi = (((size_t)(b * 128 + ch)) << 14) + posb + pl;
      out[oi] = tile[pl * 129 + ch] * s + sh + resid[oi];
    }
  }
}

// NCHW fp32 -> NHWC bf16, LDS-tiled (coalesced loads AND stores)
__global__ __launch_bounds__(256, 4)
void xcvt3(const float* __restrict__ x, unsigned short* __restrict__ xb)
{
  __shared__ unsigned tile[64 * 69];
  const int b   = blockIdx.y;
  const int p0  = blockIdx.x * 64;
  const int tid = threadIdx.x;
  const int pl  = tid & 63;
  const int cg  = tid >> 6;
  const float* __restrict__ xp = x + (((size_t)(b * C) + cg * 32) << 14) + p0 + pl;
  #pragma unroll
  for (int j = 0; j < 16; ++j) {
    const float a = xp[(size_t)(2 * j) << 14];
    const float c = xp[(size_t)(2 * j + 1) << 14];
    tile[pl * 69 + cg * 16 + j] = pack2bf(a, c);
  }
  __syncthreads();
  const int pl2 = tid >> 2;
  const int cq  = tid & 3;
  unsigned* dst = (unsigned*)(xb + (((size_t)(b << 14)) + p0 + pl2) * C + cq * 32);
  #pragma unroll
  for (int k = 0; k < 16; k += 4) {
    uint4 v;
    v.x = tile[pl2 * 69 + cq * 16 + k];
    v.y = tile[pl2 * 69 + cq * 16 + k + 1];
    v.z = tile[pl2 * 69 + cq * 16 + k + 2];
    v.w = tile[pl2 * 69 + cq * 16 + k + 3];
    *(uint4*)(dst + k) = v;
  }
}

// Swizzled weights. Deform wS unchanged: [((ch*8+ot)*64+lane)*8+j] =
// w[o=ot*16+(lane&15)][c=(ch&3)*32+(lane>>4)*8+j][tap=ch>>2] (ch<36);
// ch==36: BN-shift col. Offset/mask wOM NOW PER-HALF: col lc=lane&15 of half
// ot: tap T=(ot?5:0)+lc/3, comp=lc%3 (comp0/1=oy/ox weight row, comp2=mask);
// lc>=nom -> 0. bias likewise [half*16+lc].
__global__ void prep5(const float* __restrict__ w1, const float* __restrict__ w2,
                      const float* __restrict__ ow1, const float* __restrict__ mw1,
                      const float* __restrict__ ob1, const float* __restrict__ mb1,
                      const float* __restrict__ ow2, const float* __restrict__ mw2,
                      const float* __restrict__ ob2, const float* __restrict__ mb2,
                      const float* __restrict__ g, const float* __restrict__ bb,
                      const float* __restrict__ m, const float* __restrict__ v,
                      unsigned short* __restrict__ wb1, unsigned short* __restrict__ wb2,
                      unsigned short* __restrict__ wom1, unsigned short* __restrict__ wom2,
                      float* __restrict__ bias1, float* __restrict__ bias2)
{
  const int i = blockIdx.x * 256 + threadIdx.x;
  if (i < 128 * KT2) {              // deform, NT=8 (unchanged)
    const int j = i & 7, lane = (i >> 3) & 63, ot = (i >> 9) & 7, ch = i >> 12;
    const int o = ot * 16 + (lane & 15);
    const int qj = ((lane >> 4) << 3) + j;
    unsigned short v1 = 0, v2 = 0;
    if (ch < 36) {
      const int tap = ch >> 2;
      const int c   = ((ch & 3) << 5) + qj;
      const float s = g[c] * rsqrtf(v[c] + 1e-5f);
      v1 = f2bf(w1[(size_t)(o * 128 + c) * 9 + tap] * s);
      v2 = f2bf(w2[(size_t)(o * 128 + c) * 9 + tap]);
    } else if (qj < KK) {
      float acc = 0.f;
      for (int c = 0; c < 128; ++c) {
        const float s  = g[c] * rsqrtf(v[c] + 1e-5f);
        const float sh = bb[c] - m[c] * s;
        acc += w1[(size_t)(o * 128 + c) * 9 + qj] * sh;
      }
      v1 = f2bf(acc);
    }
    wb1[i] = v1; wb2[i] = v2;
  }
  if (i < 32 * KT2) {               // offset/mask, per-half permuted cols
    const int j = i & 7, lane = (i >> 3) & 63, ot = (i >> 9) & 1, ch = i >> 10;
    const int lc = lane & 15;
    const int qj = ((lane >> 4) << 3) + j;
    const int nom = ot ? 12 : 15;
    unsigned short v1 = 0, v2 = 0;
    if (lc < nom) {
      const int T    = (ot ? 5 : 0) + lc / 3;
      const int comp = lc - 3 * (lc / 3);
      const float* src1 = (comp == 0) ? ow1 + (size_t)(2 * T) * 1152
                        : (comp == 1) ? ow1 + (size_t)(2 * T + 1) * 1152
                                      : mw1 + (size_t)T * 1152;
      const float* src2 = (comp == 0) ? ow2 + (size_t)(2 * T) * 1152
                        : (comp == 1) ? ow2 + (size_t)(2 * T + 1) * 1152
                                      : mw2 + (size_t)T * 1152;
      if (ch < 36) {
        const int tap = ch >> 2;
        const int c   = ((ch & 3) << 5) + qj;
        const float s = g[c] * rsqrtf(v[c] + 1e-5f);
        v1 = f2bf(src1[(size_t)c * 9 + tap] * s);
        v2 = f2bf(src2[(size_t)c * 9 + tap]);
      } else if (qj < KK) {
        float acc = 0.f;
        for (int c = 0; c < 128; ++c) {
          const float s  = g[c] * rsqrtf(v[c] + 1e-5f);
          const float sh = bb[c] - m[c] * s;
          acc += src1[(size_t)c * 9 + qj] * sh;
        }
        v1 = f2bf(acc);
      }
    }
    wom1[i] = v1; wom2[i] = v2;
  }
  if (i < 32) {
    const int half = i >> 4, lc = i & 15;
    const int nom = half ? 12 : 15;
    float b1 = 0.f, b2 = 0.f;
    if (lc < nom) {
      const int T    = (half ? 5 : 0) + lc / 3;
      const int comp = lc - 3 * (lc / 3);
      b1 = (comp == 0) ? ob1[2 * T] : (comp == 1) ? ob1[2 * T + 1] : mb1[T];
      b2 = (comp == 0) ? ob2[2 * T] : (comp == 1) ? ob2[2 * T + 1] : mb2[T];
    }
    bias1[i] = b1; bias2[i] = b2;
  }
}

extern "C" void kernel_launch(void* const* d_in, const int* in_sizes, int n_in,
                              void* d_out, int out_size, void* d_ws, size_t ws_size,
                              hipStream_t stream)
{
  const float* x     = (const float*)d_in[0];
  const float* bn1g  = (const float*)d_in[1];
  const float* bn1b  = (const float*)d_in[2];
  const float* bn1m  = (const float*)d_in[3];
  const float* bn1v  = (const float*)d_in[4];
  const float* ow1   = (const float*)d_in[5];
  const float* ob1   = (const float*)d_in[6];
  const float* mw1   = (const float*)d_in[7];
  const float* mb1   = (const float*)d_in[8];
  const float* w1    = (const float*)d_in[9];
  const float* alpha = (const float*)d_in[10];
  const float* ow2   = (const float*)d_in[11];
  const float* ob2   = (const float*)d_in[12];
  const float* mw2   = (const float*)d_in[13];
  const float* mb2   = (const float*)d_in[14];
  const float* w2    = (const float*)d_in[15];
  const float* bn2g  = (const float*)d_in[16];
  const float* bn2b  = (const float*)d_in[17];
  const float* bn2m  = (const float*)d_in[18];
  const float* bn2v  = (const float*)d_in[19];
  float* out = (float*)d_out;

  char* wsp = (char*)d_ws;
  unsigned short* xbf  = (unsigned short*)(wsp);             // NHWC bf16
  unsigned short* r2bf = (unsigned short*)(wsp + 16777216);  // NHWC bf16
  unsigned short* wb1  = (unsigned short*)(wsp + 40632320);  // 303104
  unsigned short* wb2  = (unsigned short*)(wsp + 40935424);  // 303104
  unsigned short* wom1 = (unsigned short*)(wsp + 41238528);  // 75776
  unsigned short* wom2 = (unsigned short*)(wsp + 41314304);  // 75776
  float* bias1 = (float*)(wsp + 41390080);
  float* bias2 = (float*)(wsp + 41390208);
  float* part0 = (float*)(wsp + 50331648);                   // 33554432
  float* part1 = (float*)(wsp + 83886080);                   // 33554432

  xcvt3<<<dim3(256, 4), 256, 0, stream>>>(x, xbf);
  prep5<<<(128 * KT2 + 255) / 256, 256, 0, stream>>>(
      w1, w2, ow1, mw1, ob1, mb1, ow2, mw2, ob2, mb2,
      bn1g, bn1b, bn1m, bn1v, wb1, wb2, wom1, wom2, bias1, bias2);

  fusedL<1><<<2048, 256, 0, stream>>>(xbf, wom1, wb1, bias1, part0, part1);
  combL1<<<8192, 256, 0, stream>>>(part0, part1, alpha, r2bf);
  fusedL<2><<<2048, 256, 0, stream>>>(r2bf, wom2, wb2, bias2, part0, part1);
  combL2<<<dim3(256, 4), 256, 0, stream>>>(part0, part1, bn2g, bn2b, bn2m,
                                           bn2v, x, out);
}

// Round 5
// 304.274 us; speedup vs baseline: 1.5837x; 1.5837x over previous
//
#include <hip/hip_runtime.h>
#include <hip/hip_bf16.h>
#include <hip/hip_fp16.h>
#include <math.h>

#define DEV_INLINE __device__ __forceinline__

typedef __attribute__((ext_vector_type(8))) short short8;
typedef __attribute__((ext_vector_type(8))) unsigned short ushort8v;
typedef __attribute__((ext_vector_type(4))) float f32x4;

constexpr int H = 128, W = 128, C = 128, B = 4;
constexpr int KK = 9;
constexpr int KT2 = 1184;         // 37 chunks * 32

DEV_INLINE unsigned short f2bf(float f) {
  union { float f; unsigned u; } v; v.f = f;
  unsigned r = v.u + 0x7FFFu + ((v.u >> 16) & 1u);   // RNE
  return (unsigned short)(r >> 16);
}
DEV_INLINE float ubits(unsigned u) {
  union { unsigned u; float f; } v; v.u = u; return v.f;
}
DEV_INLINE unsigned pack2bf(float a, float b) {
  float2 t; t.x = a; t.y = b;
  __hip_bfloat162 h = __float22bfloat162_rn(t);
  union { __hip_bfloat162 h; unsigned u; } c; c.h = h;
  return c.u;
}
DEV_INLINE unsigned f2h2(float a, float b) {
  __half2 h = __floats2half2_rn(a, b);
  union { __half2 h; unsigned u; } c; c.h = h;
  return c.u;
}
DEV_INLINE float2 h2f2(unsigned u) {
  union { unsigned u; __half2 h; } c; c.u = u;
  return __half22float2(c.h);
}
// x-blend one dword of 2 bf16 channels from cols L,R -> packed fp16 pair
DEV_INLINE unsigned xblend(unsigned L, unsigned R, float wA, float wB) {
  const float l0 = ubits(L << 16), l1 = ubits(L & 0xFFFF0000u);
  const float r0 = ubits(R << 16), r1 = ubits(R & 0xFFFF0000u);
  return f2h2(wA * l0 + wB * r0, wA * l1 + wB * r1);
}
// async global->LDS, 16B per lane (wave-uniform LDS base + lane*16)
DEV_INLINE void gload_lds16(const unsigned short* g, unsigned short* l) {
  __builtin_amdgcn_global_load_lds(
      (const __attribute__((address_space(1))) unsigned*)g,
      (__attribute__((address_space(3))) unsigned*)l, 16, 0, 0);
}

// Fused deform layer (round 5). Evidence r0-r4: per-CU chunk-iteration
// throughput is CONSTANT (~970 cy) across schedules and occupancies =>
// bottleneck is the per-CU vector-memory address path: each bilinear gather
// is 64 lanes x 16B with 256B position stride = 64 cache-line visits per
// instruction (~1150 line-visits per block-chunk).
// FIX: transpose the gather. Producer/consumer split through LDS:
//   Producer (per chunk): thread t -> pos=t>>2, slice=t&3; loads 4x16B
//     (TL,TR,BL,BR) where 4 consecutive threads cover one CONTIGUOUS 64B
//     corner-run -> ~16 line-visits/instr (4x less TA work). X-blends
//     (wA,wB) in regs, packs fp16, 2x ds_write_b128 into gBuf (dbuf 8KB).
//   Consumer: 2x ds_read_b128 (T',B') + y-blend (mv*wyt, mv*wyb) -> B-frag,
//     8x {ds_read aBuf + MFMA} as before.
// sTab: [9][64] x 3 dwords {rowpair id, pk(wA,wB), pk(mv*wyt, mv*wyb)}.
// All waits are register deps -> plain __syncthreads per chunk.
// LDS: aBuf 2x8KB + gBuf 2x8KB + sTab 6912B = 39680 -> 4 blocks/CU.
// LAYER 1 (BN): +chunk 36 (A = BN1-shift cols; B = per-tap wt sums);
//   epilogue PReLU -> NHWC bf16. LAYER 2: 36 chunks; BN2 + NCHW residual.
template<int LAYER>
__global__ __launch_bounds__(256, 4)
void fusedL(const unsigned short* __restrict__ src,     // NHWC bf16
            const unsigned short* __restrict__ wOM,     // [37][2][64][8]
            const unsigned short* __restrict__ wS,      // [37][8][64][8]
            const float* __restrict__ bias,             // [32]
            const float* __restrict__ pA, const float* __restrict__ pB,
            const float* __restrict__ pM, const float* __restrict__ pV,
            const float* __restrict__ resid,
            unsigned short* __restrict__ outh,          // LAYER1 NHWC bf16
            float* __restrict__ outf)                   // LAYER2 NCHW fp32
{
  constexpr bool BN   = (LAYER == 1);
  constexpr int  NCH3 = BN ? 37 : 36;
  __shared__ __attribute__((aligned(16))) char smem[39680];
  float* sOff = (float*)smem;                            // [64][29] = 7424 B
  unsigned short* aBuf0 = (unsigned short*)smem;         // 8 KB (overlays sOff)
  unsigned short* aBuf1 = (unsigned short*)(smem + 8192);
  char* gBase = smem + 16384;        // gBuf: [2 par][2 half][64 pos][64B]
  unsigned* sTabU = (unsigned*)(smem + 32768);           // [9][64][3 dwords]

  const int tid  = threadIdx.x;
  const int lane = tid & 63;
  const int m16  = lane & 15;
  const int q    = lane >> 4;
  const int wv   = tid >> 6;

  const int raw  = blockIdx.x;                // 1024 blocks
  const int xcd  = raw & 7;
  const int slot = raw >> 3;                  // [0,128)
  const int b    = xcd >> 1;
  const int hy   = ((xcd & 1) << 6) | (slot >> 1);
  const int hx0  = (slot & 1) << 6;           // 64-wide segment
  const unsigned short* __restrict__ srcB = src + ((size_t)b << 14) * C;

  const int pos = (wv << 4) + m16;            // block-local position
  const int hx  = hx0 + pos;
  const int cbq = q << 3;
  const int ppos = tid >> 2;                  // producer position
  const int ps   = tid & 3;                   // producer 16B slice

  // ================= Phase 1: offset/mask conv (rolled, prefetched) ========
  f32x4 acc2[2];
  acc2[0] = (f32x4){0.f, 0.f, 0.f, 0.f};
  acc2[1] = (f32x4){0.f, 0.f, 0.f, 0.f};

  ushort8v pv;
  bool pvok;
  {
    const int iy = hy - 1, ix = hx - 1;       // ch=0: tap 0 (ky=0,kx=0), cg=0
    pvok = ((unsigned)iy < (unsigned)H) && ((unsigned)ix < (unsigned)W);
    const int rb = pvok ? (iy * W + ix) : 0;
    pv = *(const ushort8v*)(srcB + ((size_t)rb * C + cbq));
  }
  short8 pa0 = *(const short8*)(wOM + (size_t)lane * 8);
  short8 pa1 = *(const short8*)(wOM + (size_t)lane * 8 + 512);

  #pragma unroll 1
  for (int ch = 0; ch < 36; ++ch) {
    const short8 a0 = pa0, a1 = pa1;
    if (ch + 1 < 36) {                         // weight prefetch (L2-hot)
      const unsigned short* ap = wOM + ((size_t)((ch + 1) * 128 + lane)) * 8;
      pa0 = *(const short8*)(ap);
      pa1 = *(const short8*)(ap + 512);
    }
    ushort8v nv = pv;
    bool nok = false;
    if (ch + 1 < 36) {                         // source prefetch
      const int tapn = (ch + 1) >> 2, cgn = (ch + 1) & 3;
      const int ky = tapn / 3, kx = tapn - 3 * (tapn / 3);
      const int iy = hy + ky - 1;
      const int ix = hx + kx - 1;
      nok = ((unsigned)iy < (unsigned)H) && ((unsigned)ix < (unsigned)W);
      const int rb = nok ? (iy * W + ix) : 0;
      nv = *(const ushort8v*)(srcB + ((size_t)rb * C + (cgn << 5) + cbq));
    }
    union { ushort8v v; unsigned u[4]; short8 s; } bfr;
    bfr.v = pv;
    if (!pvok) { bfr.u[0] = 0; bfr.u[1] = 0; bfr.u[2] = 0; bfr.u[3] = 0; }
    acc2[0] = __builtin_amdgcn_mfma_f32_16x16x32_bf16(a0, bfr.s, acc2[0], 0, 0, 0);
    acc2[1] = __builtin_amdgcn_mfma_f32_16x16x32_bf16(a1, bfr.s, acc2[1], 0, 0, 0);
    pv = nv; pvok = nok;
  }
  if constexpr (BN) {   // validity column chunk
    union { unsigned u[4]; short8 s; } bfr;
    float sv[8];
    #pragma unroll
    for (int j = 0; j < 8; ++j) {
      const int kj = cbq + j;
      float s = 0.f;
      if (kj < KK) {
        const int ky = kj / 3, kx = kj - 3 * (kj / 3);
        const int iy = hy + ky - 1, ix = hx + kx - 1;
        s = (((unsigned)iy < (unsigned)H) && ((unsigned)ix < (unsigned)W)) ? 1.f : 0.f;
      }
      sv[j] = s;
    }
    #pragma unroll
    for (int t = 0; t < 4; ++t) bfr.u[t] = pack2bf(sv[2 * t], sv[2 * t + 1]);
    const unsigned short* ap = wOM + ((size_t)36 * 128 + lane) * 8;
    acc2[0] = __builtin_amdgcn_mfma_f32_16x16x32_bf16(*(const short8*)(ap), bfr.s, acc2[0], 0, 0, 0);
    acc2[1] = __builtin_amdgcn_mfma_f32_16x16x32_bf16(*(const short8*)(ap + 512), bfr.s, acc2[1], 0, 0, 0);
  }
  // epilogue -> sOff (D col = m16 -> pos, row = q*4+rg -> o)
  #pragma unroll
  for (int ot = 0; ot < 2; ++ot) {
    #pragma unroll
    for (int rg = 0; rg < 4; ++rg) {
      const int o = ot * 16 + (q << 2) + rg;
      if (o < 27) {
        float v = acc2[ot][rg] + bias[o];
        if (o >= 18) v = 2.f / (1.f + expf(-v));
        sOff[pos * 29 + o] = v;
      }
    }
  }
  __syncthreads();

  // ================= Phase 2: bilinear table -> sTab LDS ===================
  unsigned bnB0 = 0, bnB1 = 0, bnB2 = 0, bnB3 = 0;   // BN chunk B-frag (L1)
  {
    float tSum[9];
    const float* myOff = sOff + pos * 29;
    #pragma unroll
    for (int tap = 0; tap < 9; ++tap) {
      const int ky = tap / 3, kx = tap - 3 * (tap / 3);
      const float oy = myOff[2 * tap];
      const float ox = myOff[2 * tap + 1];
      const float mv = myOff[18 + tap];
      const float py = (float)(hy - 1 + ky) + oy;
      const float px = (float)(hx - 1 + kx) + ox;
      const float fy = floorf(py), fx = floorf(px);
      const float ay = py - fy, ax = px - fx;
      const int y0 = (int)fy, x0 = (int)fx;
      const int y1 = y0 + 1, x1 = x0 + 1;
      const float wyt = (1.f - ay) * (((unsigned)y0 < (unsigned)H) ? 1.f : 0.f);
      const float wyb = ay * (((unsigned)y1 < (unsigned)H) ? 1.f : 0.f);
      const int y0c = min(max(y0, 0), H - 1), y1c = min(max(y1, 0), H - 1);
      const int bx  = min(max(x0, 0), W - 2);
      float wA = 0.f, wB = 0.f;
      if (x0 == bx)          { wA = 1.f - ax; wB = ax; }
      else if (x1 == bx)     { wA = ax; }
      else if (x0 == bx + 1) { wB = 1.f - ax; }
      if (q == 0) {   // one writer per pos (all q computed identical values)
        const int tb = (tap * 64 + pos) * 3;
        sTabU[tb + 0] = (unsigned)(y0c * W + bx) | ((unsigned)(y1c * W + bx) << 16);
        sTabU[tb + 1] = f2h2(wA, wB);
        sTabU[tb + 2] = f2h2(mv * wyt, mv * wyb);
      }
      tSum[tap] = mv * (wyt + wyb) * (wA + wB);
    }
    if constexpr (BN) {  // BN-column B fragment (row k = tap index)
      float sv[8];
      #pragma unroll
      for (int j = 0; j < 8; ++j) {
        float s = 0.f;
        if (q == 0) s = tSum[j];
        else if (q == 1 && j == 0) s = tSum[8];
        sv[j] = s;
      }
      bnB0 = pack2bf(sv[0], sv[1]); bnB1 = pack2bf(sv[2], sv[3]);
      bnB2 = pack2bf(sv[4], sv[5]); bnB3 = pack2bf(sv[6], sv[7]);
    }
  }
  __syncthreads();   // sOff dead + sTab visible; aBuf0 may now be written

  // ================= Phase 3: deform GEMM (producer/consumer) ==============
  f32x4 acc[8];
  #pragma unroll
  for (int i = 0; i < 8; ++i) acc[i] = (f32x4){0.f, 0.f, 0.f, 0.f};

  // --- prologue: stage weights chunk 0; produce gBuf parity 0 (chunk 0) ---
  {
    unsigned short* dst0 = aBuf0 + (wv << 9);
    gload_lds16(wS + (size_t)tid * 8, dst0);
    gload_lds16(wS + (size_t)(256 + tid) * 8, dst0 + 2048);
  }
  unsigned idP  = sTabU[ppos * 3 + 0];
  unsigned wabP = sTabU[ppos * 3 + 1];
  {
    const unsigned short* aT = srcB + (size_t)(idP & 0xFFFFu) * C + ps * 8;
    const unsigned short* aB = srcB + (size_t)(idP >> 16) * C + ps * 8;
    union { uint4 v; unsigned u[4]; } LT, RT, LB, RB, oT, oB;
    LT.v = *(const uint4*)(aT); RT.v = *(const uint4*)(aT + C);
    LB.v = *(const uint4*)(aB); RB.v = *(const uint4*)(aB + C);
    const float2 wab = h2f2(wabP);
    #pragma unroll
    for (int d = 0; d < 4; ++d) {
      oT.u[d] = xblend(LT.u[d], RT.u[d], wab.x, wab.y);
      oB.u[d] = xblend(LB.u[d], RB.u[d], wab.x, wab.y);
    }
    char* gd = gBase + ppos * 64 + (ps << 4);
    *(uint4*)gd = oT.v;
    *(uint4*)(gd + 4096) = oB.v;
  }
  __syncthreads();   // gBuf[0] + aBuf0 ready

  unsigned wYc = sTabU[pos * 3 + 2];   // consumer y-weights, tap 0
  #pragma unroll 1
  for (int tap = 0; tap < 9; ++tap) {
    const float2 wY = h2f2(wYc);
    #pragma unroll
    for (int cg = 0; cg < 4; ++cg) {
      const int ch = (tap << 2) + cg;
      const int p  = ch & 1;
      const bool morew = (ch + 1 < NCH3);
      const bool morep = (ch + 1 < 36);
      // ---- stage next chunk's weights (async, other buffer) ----
      if (morew) {
        unsigned short* wd = ((cg + 1) & 1) ? aBuf1 : aBuf0;
        unsigned short* dst = wd + (wv << 9);
        const size_t gb = (size_t)(ch + 1) * 4096;
        gload_lds16(wS + gb + (size_t)tid * 8, dst);
        gload_lds16(wS + gb + (size_t)(256 + tid) * 8, dst + 2048);
      }
      // ---- producer: refresh tap entry at boundary, issue coalesced loads
      if (cg == 3 && tap < 8) {
        idP  = sTabU[((tap + 1) * 64 + ppos) * 3 + 0];
        wabP = sTabU[((tap + 1) * 64 + ppos) * 3 + 1];
      }
      union { uint4 v; unsigned u[4]; } LT, RT, LB, RB;
      if (morep) {
        const int cbn = ((cg + 1) & 3) << 5;
        const unsigned short* aT = srcB + (size_t)(idP & 0xFFFFu) * C + cbn + ps * 8;
        const unsigned short* aB = srcB + (size_t)(idP >> 16) * C + cbn + ps * 8;
        LT.v = *(const uint4*)(aT); RT.v = *(const uint4*)(aT + C);
        LB.v = *(const uint4*)(aB); RB.v = *(const uint4*)(aB + C);
      }
      // ---- consumer: y-blend from gBuf[p] -> B fragment ----
      union { uint4 v; unsigned u[4]; } Tb, Bb;
      Tb.v = *(const uint4*)(gBase + p * 8192 +        pos * 64 + (q << 4));
      Bb.v = *(const uint4*)(gBase + p * 8192 + 4096 + pos * 64 + (q << 4));
      union { unsigned u[4]; short8 s; } bfr;
      #pragma unroll
      for (int d = 0; d < 4; ++d) {
        const float2 tf = h2f2(Tb.u[d]);
        const float2 bf = h2f2(Bb.u[d]);
        bfr.u[d] = pack2bf(wY.x * tf.x + wY.y * bf.x,
                           wY.x * tf.y + wY.y * bf.y);
      }
      // ---- A-fragments from LDS + MFMA ----
      const unsigned short* rbuf = p ? aBuf1 : aBuf0;
      #pragma unroll
      for (int ot = 0; ot < 8; ++ot) {
        const short8 afr = *(const short8*)(rbuf + ((size_t)(ot * 64 + lane)) * 8);
        acc[ot] = __builtin_amdgcn_mfma_f32_16x16x32_bf16(afr, bfr.s, acc[ot], 0, 0, 0);
      }
      // ---- producer: x-blend + write gBuf[!p] for chunk ch+1 ----
      if (morep) {
        const float2 wab = h2f2(wabP);
        union { uint4 v; unsigned u[4]; } oT, oB;
        #pragma unroll
        for (int d = 0; d < 4; ++d) {
          oT.u[d] = xblend(LT.u[d], RT.u[d], wab.x, wab.y);
          oB.u[d] = xblend(LB.u[d], RB.u[d], wab.x, wab.y);
        }
        char* gd = gBase + (p ^ 1) * 8192 + ppos * 64 + (ps << 4);
        *(uint4*)gd = oT.v;
        *(uint4*)(gd + 4096) = oB.v;
      }
      __syncthreads();
    }
    if (tap < 8) wYc = sTabU[((tap + 1) * 64 + pos) * 3 + 2];
  }

  if constexpr (BN) {   // chunk 36: BN-shift column (B-frag precomputed)
    union { unsigned u[4]; short8 s; } bfr;
    bfr.u[0] = bnB0; bfr.u[1] = bnB1; bfr.u[2] = bnB2; bfr.u[3] = bnB3;
    #pragma unroll
    for (int ot = 0; ot < 8; ++ot) {
      const short8 afr = *(const short8*)(aBuf0 + ((size_t)(ot * 64 + lane)) * 8);
      acc[ot] = __builtin_amdgcn_mfma_f32_16x16x32_bf16(afr, bfr.s, acc[ot], 0, 0, 0);
    }
  }

  // ---- epilogue ----
  #pragma unroll
  for (int ot = 0; ot < 8; ++ot) {
    if constexpr (LAYER == 1) {
      const float a0 = pA[ot * 16 + (q << 2) + 0];
      const float a1 = pA[ot * 16 + (q << 2) + 1];
      const float a2 = pA[ot * 16 + (q << 2) + 2];
      const float a3 = pA[ot * 16 + (q << 2) + 3];
      const float v0 = acc[ot][0], v1 = acc[ot][1];
      const float v2 = acc[ot][2], v3 = acc[ot][3];
      uint2 st;
      st.x = pack2bf(v0 > 0.f ? v0 : a0 * v0, v1 > 0.f ? v1 : a1 * v1);
      st.y = pack2bf(v2 > 0.f ? v2 : a2 * v2, v3 > 0.f ? v3 : a3 * v3);
      const int n = (b << 14) + hy * W + hx;
      *(uint2*)(outh + (size_t)n * C + ot * 16 + (q << 2)) = st;
    } else {
      #pragma unroll
      for (int rg = 0; rg < 4; ++rg) {
        const int o = ot * 16 + (q << 2) + rg;
        const float vv = acc[ot][rg];
        const size_t oi = (((size_t)(b * C + o)) << 14) + hy * W + hx;
        const float s  = pA[o] * rsqrtf(pV[o] + 1e-5f);
        const float sh = pB[o] - pM[o] * s;
        outf[oi] = vv * s + sh + resid[oi];
      }
    }
  }
}

// NCHW fp32 -> NHWC bf16, LDS-tiled (coalesced loads AND stores)
__global__ __launch_bounds__(256, 4)
void xcvt3(const float* __restrict__ x, unsigned short* __restrict__ xb)
{
  __shared__ unsigned tile[64 * 69];
  const int b   = blockIdx.y;
  const int p0  = blockIdx.x * 64;
  const int tid = threadIdx.x;
  const int pl  = tid & 63;
  const int cg  = tid >> 6;
  const float* __restrict__ xp = x + (((size_t)(b * C) + cg * 32) << 14) + p0 + pl;
  #pragma unroll
  for (int j = 0; j < 16; ++j) {
    const float a = xp[(size_t)(2 * j) << 14];
    const float c = xp[(size_t)(2 * j + 1) << 14];
    tile[pl * 69 + cg * 16 + j] = pack2bf(a, c);
  }
  __syncthreads();
  const int pl2 = tid >> 2;
  const int cq  = tid & 3;
  unsigned* dst = (unsigned*)(xb + (((size_t)(b << 14)) + p0 + pl2) * C + cq * 32);
  #pragma unroll
  for (int k = 0; k < 16; k += 4) {
    uint4 v;
    v.x = tile[pl2 * 69 + cq * 16 + k];
    v.y = tile[pl2 * 69 + cq * 16 + k + 1];
    v.z = tile[pl2 * 69 + cq * 16 + k + 2];
    v.w = tile[pl2 * 69 + cq * 16 + k + 3];
    *(uint4*)(dst + k) = v;
  }
}

// Swizzled weights, tap-major chunks: wS[((ch*NT+ot)*64+lane)*8+j] =
// w[o=ot*16+(lane&15)][c=(ch&3)*32+(lane>>4)*8+j][tap=ch>>2] (ch<36);
// ch==36: BN-shift col (kj=(lane>>4)*8+j < 9), layer-1 only.
__global__ void prep5(const float* __restrict__ w1, const float* __restrict__ w2,
                      const float* __restrict__ ow1, const float* __restrict__ mw1,
                      const float* __restrict__ ob1, const float* __restrict__ mb1,
                      const float* __restrict__ ow2, const float* __restrict__ mw2,
                      const float* __restrict__ ob2, const float* __restrict__ mb2,
                      const float* __restrict__ g, const float* __restrict__ bb,
                      const float* __restrict__ m, const float* __restrict__ v,
                      unsigned short* __restrict__ wb1, unsigned short* __restrict__ wb2,
                      unsigned short* __restrict__ wom1, unsigned short* __restrict__ wom2,
                      float* __restrict__ bias1, float* __restrict__ bias2)
{
  const int i = blockIdx.x * 256 + threadIdx.x;
  if (i < 128 * KT2) {              // deform, NT=8
    const int j = i & 7, lane = (i >> 3) & 63, ot = (i >> 9) & 7, ch = i >> 12;
    const int o = ot * 16 + (lane & 15);
    const int qj = ((lane >> 4) << 3) + j;
    unsigned short v1 = 0, v2 = 0;
    if (ch < 36) {
      const int tap = ch >> 2;
      const int c   = ((ch & 3) << 5) + qj;
      const float s = g[c] * rsqrtf(v[c] + 1e-5f);
      v1 = f2bf(w1[(size_t)(o * 128 + c) * 9 + tap] * s);
      v2 = f2bf(w2[(size_t)(o * 128 + c) * 9 + tap]);
    } else if (qj < KK) {
      float acc = 0.f;
      for (int c = 0; c < 128; ++c) {
        const float s  = g[c] * rsqrtf(v[c] + 1e-5f);
        const float sh = bb[c] - m[c] * s;
        acc += w1[(size_t)(o * 128 + c) * 9 + qj] * sh;
      }
      v1 = f2bf(acc);
    }
    wb1[i] = v1; wb2[i] = v2;
  }
  if (i < 32 * KT2) {               // offset/mask, NT=2
    const int j = i & 7, lane = (i >> 3) & 63, ot = (i >> 9) & 1, ch = i >> 10;
    const int o = ot * 16 + (lane & 15);
    const int qj = ((lane >> 4) << 3) + j;
    unsigned short v1 = 0, v2 = 0;
    if (ch < 36) {
      const int tap = ch >> 2;
      const int c   = ((ch & 3) << 5) + qj;
      const float s = g[c] * rsqrtf(v[c] + 1e-5f);
      if (o < 18) {
        v1 = f2bf(ow1[(size_t)(o * 128 + c) * 9 + tap] * s);
        v2 = f2bf(ow2[(size_t)(o * 128 + c) * 9 + tap]);
      } else if (o < 27) {
        v1 = f2bf(mw1[(size_t)((o - 18) * 128 + c) * 9 + tap] * s);
        v2 = f2bf(mw2[(size_t)((o - 18) * 128 + c) * 9 + tap]);
      }
    } else if (qj < KK && o < 27) {
      const float* wsrc = (o < 18) ? ow1 + (size_t)o * 1152
                                   : mw1 + (size_t)(o - 18) * 1152;
      float acc = 0.f;
      for (int c = 0; c < 128; ++c) {
        const float s  = g[c] * rsqrtf(v[c] + 1e-5f);
        const float sh = bb[c] - m[c] * s;
        acc += wsrc[(size_t)c * 9 + qj] * sh;
      }
      v1 = f2bf(acc);
    }
    wom1[i] = v1; wom2[i] = v2;
  }
  if (i < 32) {
    float b1 = 0.f, b2 = 0.f;
    if (i < 18)      { b1 = ob1[i];      b2 = ob2[i]; }
    else if (i < 27) { b1 = mb1[i - 18]; b2 = mb2[i - 18]; }
    bias1[i] = b1; bias2[i] = b2;
  }
}

extern "C" void kernel_launch(void* const* d_in, const int* in_sizes, int n_in,
                              void* d_out, int out_size, void* d_ws, size_t ws_size,
                              hipStream_t stream)
{
  const float* x     = (const float*)d_in[0];
  const float* bn1g  = (const float*)d_in[1];
  const float* bn1b  = (const float*)d_in[2];
  const float* bn1m  = (const float*)d_in[3];
  const float* bn1v  = (const float*)d_in[4];
  const float* ow1   = (const float*)d_in[5];
  const float* ob1   = (const float*)d_in[6];
  const float* mw1   = (const float*)d_in[7];
  const float* mb1   = (const float*)d_in[8];
  const float* w1    = (const float*)d_in[9];
  const float* alpha = (const float*)d_in[10];
  const float* ow2   = (const float*)d_in[11];
  const float* ob2   = (const float*)d_in[12];
  const float* mw2   = (const float*)d_in[13];
  const float* mb2   = (const float*)d_in[14];
  const float* w2    = (const float*)d_in[15];
  const float* bn2g  = (const float*)d_in[16];
  const float* bn2b  = (const float*)d_in[17];
  const float* bn2m  = (const float*)d_in[18];
  const float* bn2v  = (const float*)d_in[19];
  float* out = (float*)d_out;

  char* wsp = (char*)d_ws;
  unsigned short* xbf  = (unsigned short*)(wsp);             // NHWC bf16
  unsigned short* r2bf = (unsigned short*)(wsp + 16777216);  // NHWC bf16
  unsigned short* wb1  = (unsigned short*)(wsp + 40632320);  // 303104
  unsigned short* wb2  = (unsigned short*)(wsp + 40935424);  // 303104
  unsigned short* wom1 = (unsigned short*)(wsp + 41238528);  // 75776
  unsigned short* wom2 = (unsigned short*)(wsp + 41314304);  // 75776
  float* bias1 = (float*)(wsp + 41390080);
  float* bias2 = (float*)(wsp + 41390208);

  xcvt3<<<dim3(256, 4), 256, 0, stream>>>(x, xbf);
  prep5<<<(128 * KT2 + 255) / 256, 256, 0, stream>>>(
      w1, w2, ow1, mw1, ob1, mb1, ow2, mw2, ob2, mb2,
      bn1g, bn1b, bn1m, bn1v, wb1, wb2, wom1, wom2, bias1, bias2);

  fusedL<1><<<1024, 256, 0, stream>>>(xbf, wom1, wb1, bias1, alpha,
      nullptr, nullptr, nullptr, nullptr, r2bf, nullptr);
  fusedL<2><<<1024, 256, 0, stream>>>(r2bf, wom2, wb2, bias2, bn2g,
      bn2b, bn2m, bn2v, x, nullptr, out);
}

// Round 6
// 274.063 us; speedup vs baseline: 1.7583x; 1.1102x over previous
//
#include <hip/hip_runtime.h>
#include <hip/hip_bf16.h>
#include <hip/hip_fp16.h>
#include <math.h>

#define DEV_INLINE __device__ __forceinline__

typedef __attribute__((ext_vector_type(8))) short short8;
typedef __attribute__((ext_vector_type(8))) unsigned short ushort8v;
typedef __attribute__((ext_vector_type(4))) float f32x4;

constexpr int H = 128, W = 128, C = 128, B = 4;
constexpr int KK = 9;
constexpr int KT2 = 1184;         // 37 chunks * 32
constexpr int GP = 80;            // gBuf row pitch (bytes): bank-spread
constexpr int GHALF = 64 * GP;    // one gBuf parity = 5120 B

DEV_INLINE unsigned short f2bf(float f) {
  union { float f; unsigned u; } v; v.f = f;
  unsigned r = v.u + 0x7FFFu + ((v.u >> 16) & 1u);   // RNE
  return (unsigned short)(r >> 16);
}
DEV_INLINE float ubits(unsigned u) {
  union { unsigned u; float f; } v; v.u = u; return v.f;
}
DEV_INLINE unsigned pack2bf(float a, float b) {
  float2 t; t.x = a; t.y = b;
  __hip_bfloat162 h = __float22bfloat162_rn(t);
  union { __hip_bfloat162 h; unsigned u; } c; c.h = h;
  return c.u;
}
DEV_INLINE unsigned f2h2(float a, float b) {
  __half2 h = __floats2half2_rn(a, b);
  union { __half2 h; unsigned u; } c; c.h = h;
  return c.u;
}
DEV_INLINE float2 h2f2(unsigned u) {
  union { unsigned u; __half2 h; } c; c.u = u;
  return __half22float2(c.h);
}
// full bilinear blend of one dword (2 bf16 channels) from 4 corners
DEV_INLINE unsigned blend4(unsigned TL, unsigned TR, unsigned BL, unsigned BR,
                           float w00, float w01, float w10, float w11) {
  const float lo = w00 * ubits(TL << 16) + w01 * ubits(TR << 16)
                 + w10 * ubits(BL << 16) + w11 * ubits(BR << 16);
  const float hi = w00 * ubits(TL & 0xFFFF0000u) + w01 * ubits(TR & 0xFFFF0000u)
                 + w10 * ubits(BL & 0xFFFF0000u) + w11 * ubits(BR & 0xFFFF0000u);
  return pack2bf(lo, hi);
}
// async global->LDS, 16B per lane (wave-uniform LDS base + lane*16)
DEV_INLINE void gload_lds16(const unsigned short* g, unsigned short* l) {
  __builtin_amdgcn_global_load_lds(
      (const __attribute__((address_space(1))) unsigned*)g,
      (__attribute__((address_space(3))) unsigned*)l, 16, 0, 0);
}

// Fused deform layer (round 6). r5 analysis: LDS data path ~80% busy in
// phase 3 (56 b128-ops/block-chunk, aBuf A-reads = 32 of them, all 4 waves
// reading the SAME 8 fragments); phase 1 still TA-divergent (64 lines/instr).
// Changes:
//  * Wave re-tiling: wave w computes out-tiles {2w,2w+1} x 4 pos-groups.
//    A-reads 8->2 per wave; B-frag per pos-group = ONE ds_read_b128.
//  * Producer does the FULL bilinear blend (x+y, 4 premultiplied fp16
//    weights in sTab) -> gBuf holds final bf16 samples; consumer blend VALU
//    eliminated; gBuf writes halve. LDS ops 56 -> 36 per block-chunk.
//  * Phase 1 producer-ized: coalesced 4-thread/position copy into gBuf
//    (boundary-zeroed) -> TA visits ~4x down; B-repack eliminated.
//  * gBuf pitch 80 B (bank-spread). LDS 33.5 KB, 4 blocks/CU.
// Chunk ch<36: tap=ch>>2, cg=ch&3. LAYER 1 (BN): +chunk 36 (A = BN1-shift
// cols; B = per-tap wt sums read from sTab); epilogue PReLU -> NHWC bf16.
// LAYER 2: 36 chunks; BN2 + NCHW residual.
template<int LAYER>
__global__ __launch_bounds__(256, 4)
void fusedL(const unsigned short* __restrict__ src,     // NHWC bf16
            const unsigned short* __restrict__ wOM,     // [37][2][64][8]
            const unsigned short* __restrict__ wS,      // [37][8][64][8]
            const float* __restrict__ bias,             // [32]
            const float* __restrict__ pA, const float* __restrict__ pB,
            const float* __restrict__ pM, const float* __restrict__ pV,
            const float* __restrict__ resid,
            unsigned short* __restrict__ outh,          // LAYER1 NHWC bf16
            float* __restrict__ outf)                   // LAYER2 NCHW fp32
{
  constexpr bool BN   = (LAYER == 1);
  constexpr int  NCH3 = BN ? 37 : 36;
  __shared__ __attribute__((aligned(16))) char smem[33536];
  float* sOff = (float*)smem;                            // [64][29] = 7424 B
  unsigned short* aBuf0 = (unsigned short*)smem;         // 8 KB (overlays sOff)
  unsigned short* aBuf1 = (unsigned short*)(smem + 8192);
  char* gBuf = smem + 16384;                             // [2][64][GP] = 10240
  unsigned* sTabU = (unsigned*)(smem + 26624);           // [9][64][3 dwords]

  const int tid  = threadIdx.x;
  const int lane = tid & 63;
  const int m16  = lane & 15;
  const int q    = lane >> 4;
  const int wv   = tid >> 6;

  const int raw  = blockIdx.x;                // 1024 blocks
  const int xcd  = raw & 7;
  const int slot = raw >> 3;                  // [0,128)
  const int b    = xcd >> 1;
  const int hy   = ((xcd & 1) << 6) | (slot >> 1);
  const int hx0  = (slot & 1) << 6;           // 64-wide segment
  const unsigned short* __restrict__ srcB = src + ((size_t)b << 14) * C;

  const int pos  = (wv << 4) + m16;           // phase-1/2 position
  const int ppos = tid >> 2;                  // producer position
  const int ps   = tid & 3;                   // producer 16B slice (8 ch)

  // ================= Phase 1: offset/mask conv (producer-staged) ===========
  f32x4 acc2[2];
  acc2[0] = (f32x4){0.f, 0.f, 0.f, 0.f};
  acc2[1] = (f32x4){0.f, 0.f, 0.f, 0.f};

  // prologue: produce chunk 0 (tap 0: ky=0,kx=0, cg=0) into gBuf parity 0
  {
    const int iy = hy - 1, ix = hx0 + ppos - 1;
    uint4 v; v.x = 0; v.y = 0; v.z = 0; v.w = 0;
    if (((unsigned)iy < (unsigned)H) && ((unsigned)ix < (unsigned)W))
      v = *(const uint4*)(srcB + (size_t)(iy * W + ix) * C + (ps << 3));
    *(uint4*)(gBuf + ppos * GP + (ps << 4)) = v;
  }
  short8 pa0 = *(const short8*)(wOM + (size_t)lane * 8);
  short8 pa1 = *(const short8*)(wOM + (size_t)lane * 8 + 512);
  __syncthreads();

  #pragma unroll 1
  for (int ch = 0; ch < 36; ++ch) {
    const short8 a0 = pa0, a1 = pa1;
    if (ch + 1 < 36) {                         // weight prefetch (L1/L2-hot)
      const unsigned short* ap = wOM + ((size_t)((ch + 1) * 128 + lane)) * 8;
      pa0 = *(const short8*)(ap);
      pa1 = *(const short8*)(ap + 512);
    }
    uint4 nv; nv.x = 0; nv.y = 0; nv.z = 0; nv.w = 0;
    if (ch + 1 < 36) {                         // producer: coalesced source
      const int tapn = (ch + 1) >> 2, cgn = (ch + 1) & 3;
      const int ky = tapn / 3, kx = tapn - 3 * (tapn / 3);
      const int iy = hy + ky - 1;
      const int ix = hx0 + ppos + kx - 1;
      if (((unsigned)iy < (unsigned)H) && ((unsigned)ix < (unsigned)W))
        nv = *(const uint4*)(srcB + (size_t)(iy * W + ix) * C + (cgn << 5) + (ps << 3));
    }
    // consumer: direct B-frag read (bf16 NHWC order, zero-filled if OOB)
    const short8 bfrg = *(const short8*)(gBuf + (ch & 1) * GHALF + pos * GP + (q << 4));
    acc2[0] = __builtin_amdgcn_mfma_f32_16x16x32_bf16(a0, bfrg, acc2[0], 0, 0, 0);
    acc2[1] = __builtin_amdgcn_mfma_f32_16x16x32_bf16(a1, bfrg, acc2[1], 0, 0, 0);
    if (ch + 1 < 36) {
      *(uint4*)(gBuf + ((ch + 1) & 1) * GHALF + ppos * GP + (ps << 4)) = nv;
      __syncthreads();
    }
  }
  if constexpr (BN) {   // validity column chunk (register-built B)
    union { unsigned u[4]; short8 s; } bfr;
    float sv[8];
    #pragma unroll
    for (int j = 0; j < 8; ++j) {
      const int kj = (q << 3) + j;
      float s = 0.f;
      if (kj < KK) {
        const int ky = kj / 3, kx = kj - 3 * (kj / 3);
        const int iy = hy + ky - 1, ix = hx0 + pos + kx - 1;
        s = (((unsigned)iy < (unsigned)H) && ((unsigned)ix < (unsigned)W)) ? 1.f : 0.f;
      }
      sv[j] = s;
    }
    #pragma unroll
    for (int t = 0; t < 4; ++t) bfr.u[t] = pack2bf(sv[2 * t], sv[2 * t + 1]);
    const unsigned short* ap = wOM + ((size_t)36 * 128 + lane) * 8;
    acc2[0] = __builtin_amdgcn_mfma_f32_16x16x32_bf16(*(const short8*)(ap), bfr.s, acc2[0], 0, 0, 0);
    acc2[1] = __builtin_amdgcn_mfma_f32_16x16x32_bf16(*(const short8*)(ap + 512), bfr.s, acc2[1], 0, 0, 0);
  }
  __syncthreads();   // gBuf traffic done; sOff (aBuf0 region) may be written
  // epilogue -> sOff (D col = m16 -> pos, row = q*4+rg -> o)
  #pragma unroll
  for (int ot = 0; ot < 2; ++ot) {
    #pragma unroll
    for (int rg = 0; rg < 4; ++rg) {
      const int o = ot * 16 + (q << 2) + rg;
      if (o < 27) {
        float v = acc2[ot][rg] + bias[o];
        if (o >= 18) v = 2.f / (1.f + expf(-v));
        sOff[pos * 29 + o] = v;
      }
    }
  }
  __syncthreads();

  // ================= Phase 2: bilinear table -> sTab LDS ===================
  // entry: {rowpair id, pk(w00,w01), pk(w10,w11)}, w = mv*wy*wx premultiplied
  {
    const float* myOff = sOff + pos * 29;
    #pragma unroll
    for (int tap = 0; tap < 9; ++tap) {
      const int ky = tap / 3, kx = tap - 3 * (tap / 3);
      const float oy = myOff[2 * tap];
      const float ox = myOff[2 * tap + 1];
      const float mv = myOff[18 + tap];
      const float py = (float)(hy - 1 + ky) + oy;
      const float px = (float)(hx0 + pos - 1 + kx) + ox;
      const float fy = floorf(py), fx = floorf(px);
      const float ay = py - fy, ax = px - fx;
      const int y0 = (int)fy, x0 = (int)fx;
      const int y1 = y0 + 1, x1 = x0 + 1;
      const float wyt = (1.f - ay) * (((unsigned)y0 < (unsigned)H) ? 1.f : 0.f);
      const float wyb = ay * (((unsigned)y1 < (unsigned)H) ? 1.f : 0.f);
      const int y0c = min(max(y0, 0), H - 1), y1c = min(max(y1, 0), H - 1);
      const int bx  = min(max(x0, 0), W - 2);
      float wA = 0.f, wB = 0.f;
      if (x0 == bx)          { wA = 1.f - ax; wB = ax; }
      else if (x1 == bx)     { wA = ax; }
      else if (x0 == bx + 1) { wB = 1.f - ax; }
      if (q == 0) {   // one writer per pos
        const int tb = (tap * 64 + pos) * 3;
        sTabU[tb + 0] = (unsigned)(y0c * W + bx) | ((unsigned)(y1c * W + bx) << 16);
        sTabU[tb + 1] = f2h2(mv * wyt * wA, mv * wyt * wB);
        sTabU[tb + 2] = f2h2(mv * wyb * wA, mv * wyb * wB);
      }
    }
  }
  __syncthreads();   // sOff dead + sTab visible; aBuf0 may now be staged

  // ================= Phase 3: deform GEMM (re-tiled, full-blend producer) ==
  f32x4 acc[2][4];
  #pragma unroll
  for (int i = 0; i < 2; ++i)
    #pragma unroll
    for (int j = 0; j < 4; ++j) acc[i][j] = (f32x4){0.f, 0.f, 0.f, 0.f};

  // prologue: stage chunk 0 weights; produce gBuf[0] (chunk 0, tap 0)
  {
    unsigned short* dst0 = aBuf0 + (wv << 9);
    gload_lds16(wS + (size_t)tid * 8, dst0);
    gload_lds16(wS + (size_t)(256 + tid) * 8, dst0 + 2048);
  }
  unsigned pid, pw0, pw1;
  {
    const int tb = ppos * 3;
    pid = sTabU[tb]; pw0 = sTabU[tb + 1]; pw1 = sTabU[tb + 2];
    const unsigned short* pT  = srcB + (size_t)(pid & 0xFFFFu) * C + (ps << 3);
    const unsigned short* pBm = srcB + (size_t)(pid >> 16) * C + (ps << 3);
    const uint4 TL = *(const uint4*)(pT),  TR = *(const uint4*)(pT + C);
    const uint4 BL = *(const uint4*)(pBm), BR = *(const uint4*)(pBm + C);
    const float2 wa = h2f2(pw0), wb = h2f2(pw1);
    uint4 o;
    o.x = blend4(TL.x, TR.x, BL.x, BR.x, wa.x, wa.y, wb.x, wb.y);
    o.y = blend4(TL.y, TR.y, BL.y, BR.y, wa.x, wa.y, wb.x, wb.y);
    o.z = blend4(TL.z, TR.z, BL.z, BR.z, wa.x, wa.y, wb.x, wb.y);
    o.w = blend4(TL.w, TR.w, BL.w, BR.w, wa.x, wa.y, wb.x, wb.y);
    *(uint4*)(gBuf + ppos * GP + (ps << 4)) = o;
  }
  __syncthreads();   // aBuf0 staged (vmcnt drained) + gBuf[0] ready

  #pragma unroll 1
  for (int ch = 0; ch < 36; ++ch) {
    const int p = ch & 1;
    const bool morew = (ch + 1 < NCH3);
    const bool morep = (ch + 1 < 36);
    // ---- stage next chunk's weights (async, other buffer) ----
    if (morew) {
      unsigned short* wd = ((ch + 1) & 1) ? aBuf1 : aBuf0;
      unsigned short* dst = wd + (wv << 9);
      const size_t gb = (size_t)(ch + 1) * 4096;
      gload_lds16(wS + gb + (size_t)tid * 8, dst);
      gload_lds16(wS + gb + (size_t)(256 + tid) * 8, dst + 2048);
    }
    // ---- producer: refresh tap entry at boundary, issue corner loads ----
    if (morep && (((ch + 1) & 3) == 0)) {
      const int tb = (((ch + 1) >> 2) * 64 + ppos) * 3;
      pid = sTabU[tb]; pw0 = sTabU[tb + 1]; pw1 = sTabU[tb + 2];
    }
    uint4 TL, TR, BL, BR;
    if (morep) {
      const int cbn = (((ch + 1) & 3) << 5) + (ps << 3);
      const unsigned short* pT  = srcB + (size_t)(pid & 0xFFFFu) * C + cbn;
      const unsigned short* pBm = srcB + (size_t)(pid >> 16) * C + cbn;
      TL = *(const uint4*)(pT);  TR = *(const uint4*)(pT + C);
      BL = *(const uint4*)(pBm); BR = *(const uint4*)(pBm + C);
    }
    // ---- consumer: 2 A-frags (own out-tiles) + 4 B-frags (pos-groups) ----
    const unsigned short* rbuf = p ? aBuf1 : aBuf0;
    const short8 af0 = *(const short8*)(rbuf + ((size_t)((2 * wv) * 64 + lane)) * 8);
    const short8 af1 = *(const short8*)(rbuf + ((size_t)((2 * wv + 1) * 64 + lane)) * 8);
    const char* gb = gBuf + p * GHALF;
    short8 bf[4];
    #pragma unroll
    for (int pg = 0; pg < 4; ++pg)
      bf[pg] = *(const short8*)(gb + (pg * 16 + m16) * GP + (q << 4));
    #pragma unroll
    for (int pg = 0; pg < 4; ++pg) {
      acc[0][pg] = __builtin_amdgcn_mfma_f32_16x16x32_bf16(af0, bf[pg], acc[0][pg], 0, 0, 0);
      acc[1][pg] = __builtin_amdgcn_mfma_f32_16x16x32_bf16(af1, bf[pg], acc[1][pg], 0, 0, 0);
    }
    // ---- producer: full blend + single write ----
    if (morep) {
      const float2 wa = h2f2(pw0), wb = h2f2(pw1);
      uint4 o;
      o.x = blend4(TL.x, TR.x, BL.x, BR.x, wa.x, wa.y, wb.x, wb.y);
      o.y = blend4(TL.y, TR.y, BL.y, BR.y, wa.x, wa.y, wb.x, wb.y);
      o.z = blend4(TL.z, TR.z, BL.z, BR.z, wa.x, wa.y, wb.x, wb.y);
      o.w = blend4(TL.w, TR.w, BL.w, BR.w, wa.x, wa.y, wb.x, wb.y);
      *(uint4*)(gBuf + (p ^ 1) * GHALF + ppos * GP + (ps << 4)) = o;
    }
    if (morew) __syncthreads();
  }

  if constexpr (BN) {   // chunk 36: BN-shift column; B = per-tap sums (sTab)
    const short8 af0 = *(const short8*)(aBuf0 + ((size_t)((2 * wv) * 64 + lane)) * 8);
    const short8 af1 = *(const short8*)(aBuf0 + ((size_t)((2 * wv + 1) * 64 + lane)) * 8);
    #pragma unroll
    for (int pg = 0; pg < 4; ++pg) {
      float sv[8];
      #pragma unroll
      for (int j = 0; j < 8; ++j) {
        const int k = (q << 3) + j;
        float s = 0.f;
        if (k < KK) {
          const int tb = (k * 64 + pg * 16 + m16) * 3;
          const float2 a = h2f2(sTabU[tb + 1]);
          const float2 c = h2f2(sTabU[tb + 2]);
          s = a.x + a.y + c.x + c.y;
        }
        sv[j] = s;
      }
      union { unsigned u[4]; short8 s; } bfr;
      #pragma unroll
      for (int t = 0; t < 4; ++t) bfr.u[t] = pack2bf(sv[2 * t], sv[2 * t + 1]);
      acc[0][pg] = __builtin_amdgcn_mfma_f32_16x16x32_bf16(af0, bfr.s, acc[0][pg], 0, 0, 0);
      acc[1][pg] = __builtin_amdgcn_mfma_f32_16x16x32_bf16(af1, bfr.s, acc[1][pg], 0, 0, 0);
    }
  }

  // ---- epilogue ----
  #pragma unroll
  for (int oi = 0; oi < 2; ++oi) {
    const int ot = wv * 2 + oi;
    if constexpr (LAYER == 1) {
      const float a0 = pA[ot * 16 + (q << 2) + 0];
      const float a1 = pA[ot * 16 + (q << 2) + 1];
      const float a2 = pA[ot * 16 + (q << 2) + 2];
      const float a3 = pA[ot * 16 + (q << 2) + 3];
      #pragma unroll
      for (int pg = 0; pg < 4; ++pg) {
        const float v0 = acc[oi][pg][0], v1 = acc[oi][pg][1];
        const float v2 = acc[oi][pg][2], v3 = acc[oi][pg][3];
        uint2 st;
        st.x = pack2bf(v0 > 0.f ? v0 : a0 * v0, v1 > 0.f ? v1 : a1 * v1);
        st.y = pack2bf(v2 > 0.f ? v2 : a2 * v2, v3 > 0.f ? v3 : a3 * v3);
        const int n = (b << 14) + hy * W + hx0 + pg * 16 + m16;
        *(uint2*)(outh + (size_t)n * C + ot * 16 + (q << 2)) = st;
      }
    } else {
      #pragma unroll
      for (int rg = 0; rg < 4; ++rg) {
        const int o = ot * 16 + (q << 2) + rg;
        const float s  = pA[o] * rsqrtf(pV[o] + 1e-5f);
        const float sh = pB[o] - pM[o] * s;
        #pragma unroll
        for (int pg = 0; pg < 4; ++pg) {
          const size_t oi2 = (((size_t)(b * C + o)) << 14) + hy * W + hx0 + pg * 16 + m16;
          outf[oi2] = acc[oi][pg][rg] * s + sh + resid[oi2];
        }
      }
    }
  }
}

// NCHW fp32 -> NHWC bf16, LDS-tiled (coalesced loads AND stores)
__global__ __launch_bounds__(256, 4)
void xcvt3(const float* __restrict__ x, unsigned short* __restrict__ xb)
{
  __shared__ unsigned tile[64 * 69];
  const int b   = blockIdx.y;
  const int p0  = blockIdx.x * 64;
  const int tid = threadIdx.x;
  const int pl  = tid & 63;
  const int cg  = tid >> 6;
  const float* __restrict__ xp = x + (((size_t)(b * C) + cg * 32) << 14) + p0 + pl;
  #pragma unroll
  for (int j = 0; j < 16; ++j) {
    const float a = xp[(size_t)(2 * j) << 14];
    const float c = xp[(size_t)(2 * j + 1) << 14];
    tile[pl * 69 + cg * 16 + j] = pack2bf(a, c);
  }
  __syncthreads();
  const int pl2 = tid >> 2;
  const int cq  = tid & 3;
  unsigned* dst = (unsigned*)(xb + (((size_t)(b << 14)) + p0 + pl2) * C + cq * 32);
  #pragma unroll
  for (int k = 0; k < 16; k += 4) {
    uint4 v;
    v.x = tile[pl2 * 69 + cq * 16 + k];
    v.y = tile[pl2 * 69 + cq * 16 + k + 1];
    v.z = tile[pl2 * 69 + cq * 16 + k + 2];
    v.w = tile[pl2 * 69 + cq * 16 + k + 3];
    *(uint4*)(dst + k) = v;
  }
}

// Swizzled weights, tap-major chunks: wS[((ch*NT+ot)*64+lane)*8+j] =
// w[o=ot*16+(lane&15)][c=(ch&3)*32+(lane>>4)*8+j][tap=ch>>2] (ch<36);
// ch==36: BN-shift col (kj=(lane>>4)*8+j < 9), layer-1 only.
__global__ void prep5(const float* __restrict__ w1, const float* __restrict__ w2,
                      const float* __restrict__ ow1, const float* __restrict__ mw1,
                      const float* __restrict__ ob1, const float* __restrict__ mb1,
                      const float* __restrict__ ow2, const float* __restrict__ mw2,
                      const float* __restrict__ ob2, const float* __restrict__ mb2,
                      const float* __restrict__ g, const float* __restrict__ bb,
                      const float* __restrict__ m, const float* __restrict__ v,
                      unsigned short* __restrict__ wb1, unsigned short* __restrict__ wb2,
                      unsigned short* __restrict__ wom1, unsigned short* __restrict__ wom2,
                      float* __restrict__ bias1, float* __restrict__ bias2)
{
  const int i = blockIdx.x * 256 + threadIdx.x;
  if (i < 128 * KT2) {              // deform, NT=8
    const int j = i & 7, lane = (i >> 3) & 63, ot = (i >> 9) & 7, ch = i >> 12;
    const int o = ot * 16 + (lane & 15);
    const int qj = ((lane >> 4) << 3) + j;
    unsigned short v1 = 0, v2 = 0;
    if (ch < 36) {
      const int tap = ch >> 2;
      const int c   = ((ch & 3) << 5) + qj;
      const float s = g[c] * rsqrtf(v[c] + 1e-5f);
      v1 = f2bf(w1[(size_t)(o * 128 + c) * 9 + tap] * s);
      v2 = f2bf(w2[(size_t)(o * 128 + c) * 9 + tap]);
    } else if (qj < KK) {
      float acc = 0.f;
      for (int c = 0; c < 128; ++c) {
        const float s  = g[c] * rsqrtf(v[c] + 1e-5f);
        const float sh = bb[c] - m[c] * s;
        acc += w1[(size_t)(o * 128 + c) * 9 + qj] * sh;
      }
      v1 = f2bf(acc);
    }
    wb1[i] = v1; wb2[i] = v2;
  }
  if (i < 32 * KT2) {               // offset/mask, NT=2
    const int j = i & 7, lane = (i >> 3) & 63, ot = (i >> 9) & 1, ch = i >> 10;
    const int o = ot * 16 + (lane & 15);
    const int qj = ((lane >> 4) << 3) + j;
    unsigned short v1 = 0, v2 = 0;
    if (ch < 36) {
      const int tap = ch >> 2;
      const int c   = ((ch & 3) << 5) + qj;
      const float s = g[c] * rsqrtf(v[c] + 1e-5f);
      if (o < 18) {
        v1 = f2bf(ow1[(size_t)(o * 128 + c) * 9 + tap] * s);
        v2 = f2bf(ow2[(size_t)(o * 128 + c) * 9 + tap]);
      } else if (o < 27) {
        v1 = f2bf(mw1[(size_t)((o - 18) * 128 + c) * 9 + tap] * s);
        v2 = f2bf(mw2[(size_t)((o - 18) * 128 + c) * 9 + tap]);
      }
    } else if (qj < KK && o < 27) {
      const float* wsrc = (o < 18) ? ow1 + (size_t)o * 1152
                                   : mw1 + (size_t)(o - 18) * 1152;
      float acc = 0.f;
      for (int c = 0; c < 128; ++c) {
        const float s  = g[c] * rsqrtf(v[c] + 1e-5f);
        const float sh = bb[c] - m[c] * s;
        acc += wsrc[(size_t)c * 9 + qj] * sh;
      }
      v1 = f2bf(acc);
    }
    wom1[i] = v1; wom2[i] = v2;
  }
  if (i < 32) {
    float b1 = 0.f, b2 = 0.f;
    if (i < 18)      { b1 = ob1[i];      b2 = ob2[i]; }
    else if (i < 27) { b1 = mb1[i - 18]; b2 = mb2[i - 18]; }
    bias1[i] = b1; bias2[i] = b2;
  }
}

extern "C" void kernel_launch(void* const* d_in, const int* in_sizes, int n_in,
                              void* d_out, int out_size, void* d_ws, size_t ws_size,
                              hipStream_t stream)
{
  const float* x     = (const float*)d_in[0];
  const float* bn1g  = (const float*)d_in[1];
  const float* bn1b  = (const float*)d_in[2];
  const float* bn1m  = (const float*)d_in[3];
  const float* bn1v  = (const float*)d_in[4];
  const float* ow1   = (const float*)d_in[5];
  const float* ob1   = (const float*)d_in[6];
  const float* mw1   = (const float*)d_in[7];
  const float* mb1   = (const float*)d_in[8];
  const float* w1    = (const float*)d_in[9];
  const float* alpha = (const float*)d_in[10];
  const float* ow2   = (const float*)d_in[11];
  const float* ob2   = (const float*)d_in[12];
  const float* mw2   = (const float*)d_in[13];
  const float* mb2   = (const float*)d_in[14];
  const float* w2    = (const float*)d_in[15];
  const float* bn2g  = (const float*)d_in[16];
  const float* bn2b  = (const float*)d_in[17];
  const float* bn2m  = (const float*)d_in[18];
  const float* bn2v  = (const float*)d_in[19];
  float* out = (float*)d_out;

  char* wsp = (char*)d_ws;
  unsigned short* xbf  = (unsigned short*)(wsp);             // NHWC bf16
  unsigned short* r2bf = (unsigned short*)(wsp + 16777216);  // NHWC bf16
  unsigned short* wb1  = (unsigned short*)(wsp + 40632320);  // 303104
  unsigned short* wb2  = (unsigned short*)(wsp + 40935424);  // 303104
  unsigned short* wom1 = (unsigned short*)(wsp + 41238528);  // 75776
  unsigned short* wom2 = (unsigned short*)(wsp + 41314304);  // 75776
  float* bias1 = (float*)(wsp + 41390080);
  float* bias2 = (float*)(wsp + 41390208);

  xcvt3<<<dim3(256, 4), 256, 0, stream>>>(x, xbf);
  prep5<<<(128 * KT2 + 255) / 256, 256, 0, stream>>>(
      w1, w2, ow1, mw1, ob1, mb1, ow2, mw2, ob2, mb2,
      bn1g, bn1b, bn1m, bn1v, wb1, wb2, wom1, wom2, bias1, bias2);

  fusedL<1><<<1024, 256, 0, stream>>>(xbf, wom1, wb1, bias1, alpha,
      nullptr, nullptr, nullptr, nullptr, r2bf, nullptr);
  fusedL<2><<<1024, 256, 0, stream>>>(r2bf, wom2, wb2, bias2, bn2g,
      bn2b, bn2m, bn2v, x, nullptr, out);
}

// Round 7
// 257.738 us; speedup vs baseline: 1.8697x; 1.0633x over previous
//
#include <hip/hip_runtime.h>
#include <hip/hip_bf16.h>
#include <hip/hip_fp16.h>
#include <math.h>

#define DEV_INLINE __device__ __forceinline__

typedef __attribute__((ext_vector_type(8))) short short8;
typedef __attribute__((ext_vector_type(8))) unsigned short ushort8v;
typedef __attribute__((ext_vector_type(4))) float f32x4;

constexpr int H = 128, W = 128, C = 128, B = 4;
constexpr int KK = 9;
constexpr int KT2 = 1184;         // 37 chunks * 32
constexpr int GP = 80;            // gBuf row pitch (bytes): bank-spread
constexpr int GHALF = 64 * GP;    // one gBuf parity = 5120 B

DEV_INLINE unsigned short f2bf(float f) {
  union { float f; unsigned u; } v; v.f = f;
  unsigned r = v.u + 0x7FFFu + ((v.u >> 16) & 1u);   // RNE
  return (unsigned short)(r >> 16);
}
DEV_INLINE float ubits(unsigned u) {
  union { unsigned u; float f; } v; v.u = u; return v.f;
}
DEV_INLINE unsigned pack2bf(float a, float b) {
  float2 t; t.x = a; t.y = b;
  __hip_bfloat162 h = __float22bfloat162_rn(t);
  union { __hip_bfloat162 h; unsigned u; } c; c.h = h;
  return c.u;
}
DEV_INLINE unsigned f2h2(float a, float b) {
  __half2 h = __floats2half2_rn(a, b);
  union { __half2 h; unsigned u; } c; c.h = h;
  return c.u;
}
DEV_INLINE float2 h2f2(unsigned u) {
  union { unsigned u; __half2 h; } c; c.u = u;
  return __half22float2(c.h);
}
// full bilinear blend of one dword (2 bf16 channels) from 4 corners
DEV_INLINE unsigned blend4(unsigned TL, unsigned TR, unsigned BL, unsigned BR,
                           float w00, float w01, float w10, float w11) {
  const float lo = w00 * ubits(TL << 16) + w01 * ubits(TR << 16)
                 + w10 * ubits(BL << 16) + w11 * ubits(BR << 16);
  const float hi = w00 * ubits(TL & 0xFFFF0000u) + w01 * ubits(TR & 0xFFFF0000u)
                 + w10 * ubits(BL & 0xFFFF0000u) + w11 * ubits(BR & 0xFFFF0000u);
  return pack2bf(lo, hi);
}
DEV_INLINE void lgkm_barrier() {
  asm volatile("s_waitcnt lgkmcnt(0)" ::: "memory");
  __builtin_amdgcn_s_barrier();
  __builtin_amdgcn_sched_barrier(0);
}

// Fused deform layer (round 7). r6: 86.5us, VALU 50%, LDS-op count and the
// vmcnt(0)-drain at every __syncthreads (forced by global_load_lds) the
// residual costs; bank-conflict 5.4M suspected from the staging stream.
// Changes:
//  * A-fragments DIRECT from global (2 coalesced 16B/lane loads per wave per
//    chunk, L1-hot: 4KB/chunk shared by all 4 resident blocks), depth-1
//    prefetched. aBuf + global_load_lds staging DELETED.
//  * Barriers are raw s_barrier + lgkmcnt(0) ONLY (no vmem drain) -> the
//    producer's global corner loads stay in flight across barriers.
//  * Depth-2 producer pipeline in BOTH phases: corners/source for chunk ch+2
//    issued at iter ch, blended/written at iter ch+1, consumed at ch+2
//    (window ~700cy covers L1/L2 latency).
//  * #pragma unroll 2 -> gBuf parity compile-time.
// LDS: gBuf 2x5120 (sOff overlays) + sTab 6912 = 17152 B.
// Chunk ch<36: tap=ch>>2, cg=ch&3. LAYER 1 (BN): +chunk 36 (A = BN1-shift
// cols from wS[36]; B = per-tap wt sums from sTab); epilogue PReLU -> NHWC
// bf16. LAYER 2: 36 chunks; BN2 + NCHW residual.
template<int LAYER>
__global__ __launch_bounds__(256, 4)
void fusedL(const unsigned short* __restrict__ src,     // NHWC bf16
            const unsigned short* __restrict__ wOM,     // [37][2][64][8]
            const unsigned short* __restrict__ wS,      // [37][8][64][8]
            const float* __restrict__ bias,             // [32]
            const float* __restrict__ pA, const float* __restrict__ pB,
            const float* __restrict__ pM, const float* __restrict__ pV,
            const float* __restrict__ resid,
            unsigned short* __restrict__ outh,          // LAYER1 NHWC bf16
            float* __restrict__ outf)                   // LAYER2 NCHW fp32
{
  constexpr bool BN   = (LAYER == 1);
  constexpr int  NCH3 = BN ? 37 : 36;
  __shared__ __attribute__((aligned(16))) char smem[17152];
  char* gBuf = smem;                                     // [2][64][GP] = 10240
  float* sOff = (float*)smem;                            // overlays gBuf
  unsigned* sTabU = (unsigned*)(smem + 10240);           // [9][64][3 dwords]

  const int tid  = threadIdx.x;
  const int lane = tid & 63;
  const int m16  = lane & 15;
  const int q    = lane >> 4;
  const int wv   = tid >> 6;

  const int raw  = blockIdx.x;                // 1024 blocks
  const int xcd  = raw & 7;
  const int slot = raw >> 3;                  // [0,128)
  const int b    = xcd >> 1;
  const int hy   = ((xcd & 1) << 6) | (slot >> 1);
  const int hx0  = (slot & 1) << 6;           // 64-wide segment
  const unsigned short* __restrict__ srcB = src + ((size_t)b << 14) * C;

  const int pos  = (wv << 4) + m16;           // consumer position
  const int ppos = tid >> 2;                  // producer position
  const int ps   = tid & 3;                   // producer 16B slice (8 ch)

  // ================= Phase 1: offset/mask conv (depth-2 producer) ==========
  f32x4 acc2[2];
  acc2[0] = (f32x4){0.f, 0.f, 0.f, 0.f};
  acc2[1] = (f32x4){0.f, 0.f, 0.f, 0.f};

  {  // chunk 0 (tap0: ky=0,kx=0, cg=0) -> gBuf[0]
    const int iy = hy - 1, ix = hx0 + ppos - 1;
    uint4 v; v.x = 0; v.y = 0; v.z = 0; v.w = 0;
    if (((unsigned)iy < (unsigned)H) && ((unsigned)ix < (unsigned)W))
      v = *(const uint4*)(srcB + (size_t)(iy * W + ix) * C + (ps << 3));
    *(uint4*)(gBuf + ppos * GP + (ps << 4)) = v;
  }
  uint4 pendV; pendV.x = 0; pendV.y = 0; pendV.z = 0; pendV.w = 0;
  {  // pend = chunk 1 source (tap0, cg1)
    const int iy = hy - 1, ix = hx0 + ppos - 1;
    if (((unsigned)iy < (unsigned)H) && ((unsigned)ix < (unsigned)W))
      pendV = *(const uint4*)(srcB + (size_t)(iy * W + ix) * C + 32 + (ps << 3));
  }
  short8 pa0 = *(const short8*)(wOM + (size_t)lane * 8);
  short8 pa1 = *(const short8*)(wOM + (size_t)lane * 8 + 512);
  lgkm_barrier();

  #pragma unroll 2
  for (int ch = 0; ch < 36; ++ch) {
    const int p = ch & 1;
    const short8 a0 = pa0, a1 = pa1;
    if (ch + 1 < 36) {                         // weight prefetch (L1-hot)
      const unsigned short* ap = wOM + ((size_t)((ch + 1) * 128 + lane)) * 8;
      pa0 = *(const short8*)(ap);
      pa1 = *(const short8*)(ap + 512);
    }
    uint4 newV; newV.x = 0; newV.y = 0; newV.z = 0; newV.w = 0;
    if (ch + 2 < 36) {                         // producer: source for ch+2
      const int t2 = (ch + 2) >> 2, c2 = (ch + 2) & 3;
      const int ky = t2 / 3, kx = t2 - 3 * (t2 / 3);
      const int iy = hy + ky - 1;
      const int ix = hx0 + ppos + kx - 1;
      if (((unsigned)iy < (unsigned)H) && ((unsigned)ix < (unsigned)W))
        newV = *(const uint4*)(srcB + (size_t)(iy * W + ix) * C + (c2 << 5) + (ps << 3));
    }
    if (ch + 1 < 36)                           // write pend (chunk ch+1)
      *(uint4*)(gBuf + (p ^ 1) * GHALF + ppos * GP + (ps << 4)) = pendV;
    const short8 bfrg = *(const short8*)(gBuf + p * GHALF + pos * GP + (q << 4));
    acc2[0] = __builtin_amdgcn_mfma_f32_16x16x32_bf16(a0, bfrg, acc2[0], 0, 0, 0);
    acc2[1] = __builtin_amdgcn_mfma_f32_16x16x32_bf16(a1, bfrg, acc2[1], 0, 0, 0);
    pendV = newV;
    if (ch + 1 < 36) lgkm_barrier();
  }
  if constexpr (BN) {   // validity column chunk (register B, global A)
    union { unsigned u[4]; short8 s; } bfr;
    float sv[8];
    #pragma unroll
    for (int j = 0; j < 8; ++j) {
      const int kj = (q << 3) + j;
      float s = 0.f;
      if (kj < KK) {
        const int ky = kj / 3, kx = kj - 3 * (kj / 3);
        const int iy = hy + ky - 1, ix = hx0 + pos + kx - 1;
        s = (((unsigned)iy < (unsigned)H) && ((unsigned)ix < (unsigned)W)) ? 1.f : 0.f;
      }
      sv[j] = s;
    }
    #pragma unroll
    for (int t = 0; t < 4; ++t) bfr.u[t] = pack2bf(sv[2 * t], sv[2 * t + 1]);
    const unsigned short* ap = wOM + ((size_t)36 * 128 + lane) * 8;
    acc2[0] = __builtin_amdgcn_mfma_f32_16x16x32_bf16(*(const short8*)(ap), bfr.s, acc2[0], 0, 0, 0);
    acc2[1] = __builtin_amdgcn_mfma_f32_16x16x32_bf16(*(const short8*)(ap + 512), bfr.s, acc2[1], 0, 0, 0);
  }
  __syncthreads();   // gBuf reads done everywhere; sOff (overlay) may be written
  // epilogue -> sOff (D col = m16 -> pos, row = q*4+rg -> o)
  #pragma unroll
  for (int ot = 0; ot < 2; ++ot) {
    #pragma unroll
    for (int rg = 0; rg < 4; ++rg) {
      const int o = ot * 16 + (q << 2) + rg;
      if (o < 27) {
        float v = acc2[ot][rg] + bias[o];
        if (o >= 18) v = 2.f / (1.f + expf(-v));
        sOff[pos * 29 + o] = v;
      }
    }
  }
  __syncthreads();

  // ================= Phase 2: bilinear table -> sTab LDS ===================
  // entry: {rowpair id, pk(w00,w01), pk(w10,w11)}, w = mv*wy*wx premultiplied
  {
    const float* myOff = sOff + pos * 29;
    #pragma unroll
    for (int tap = 0; tap < 9; ++tap) {
      const int ky = tap / 3, kx = tap - 3 * (tap / 3);
      const float oy = myOff[2 * tap];
      const float ox = myOff[2 * tap + 1];
      const float mv = myOff[18 + tap];
      const float py = (float)(hy - 1 + ky) + oy;
      const float px = (float)(hx0 + pos - 1 + kx) + ox;
      const float fy = floorf(py), fx = floorf(px);
      const float ay = py - fy, ax = px - fx;
      const int y0 = (int)fy, x0 = (int)fx;
      const int y1 = y0 + 1, x1 = x0 + 1;
      const float wyt = (1.f - ay) * (((unsigned)y0 < (unsigned)H) ? 1.f : 0.f);
      const float wyb = ay * (((unsigned)y1 < (unsigned)H) ? 1.f : 0.f);
      const int y0c = min(max(y0, 0), H - 1), y1c = min(max(y1, 0), H - 1);
      const int bx  = min(max(x0, 0), W - 2);
      float wA = 0.f, wB = 0.f;
      if (x0 == bx)          { wA = 1.f - ax; wB = ax; }
      else if (x1 == bx)     { wA = ax; }
      else if (x0 == bx + 1) { wB = 1.f - ax; }
      if (q == 0) {   // one writer per pos
        const int tb = (tap * 64 + pos) * 3;
        sTabU[tb + 0] = (unsigned)(y0c * W + bx) | ((unsigned)(y1c * W + bx) << 16);
        sTabU[tb + 1] = f2h2(mv * wyt * wA, mv * wyt * wB);
        sTabU[tb + 2] = f2h2(mv * wyb * wA, mv * wyb * wB);
      }
    }
  }
  __syncthreads();   // sOff dead + sTab visible; gBuf may be overwritten

  // ================= Phase 3: deform GEMM (no LDS weights, depth-2) ========
  f32x4 acc[2][4];
  #pragma unroll
  for (int i = 0; i < 2; ++i)
    #pragma unroll
    for (int j = 0; j < 4; ++j) acc[i][j] = (f32x4){0.f, 0.f, 0.f, 0.f};

  unsigned tabId, tabW0, tabW1;      // entry for tap of the PENDING chunk
  {
    const int tb = ppos * 3;
    tabId = sTabU[tb]; tabW0 = sTabU[tb + 1]; tabW1 = sTabU[tb + 2];
  }
  {  // chunk 0: load + blend + write gBuf[0]
    const unsigned short* pT  = srcB + (size_t)(tabId & 0xFFFFu) * C + (ps << 3);
    const unsigned short* pBm = srcB + (size_t)(tabId >> 16) * C + (ps << 3);
    const uint4 TL = *(const uint4*)(pT),  TR = *(const uint4*)(pT + C);
    const uint4 BL = *(const uint4*)(pBm), BR = *(const uint4*)(pBm + C);
    const float2 wa = h2f2(tabW0), wb = h2f2(tabW1);
    uint4 o;
    o.x = blend4(TL.x, TR.x, BL.x, BR.x, wa.x, wa.y, wb.x, wb.y);
    o.y = blend4(TL.y, TR.y, BL.y, BR.y, wa.x, wa.y, wb.x, wb.y);
    o.z = blend4(TL.z, TR.z, BL.z, BR.z, wa.x, wa.y, wb.x, wb.y);
    o.w = blend4(TL.w, TR.w, BL.w, BR.w, wa.x, wa.y, wb.x, wb.y);
    *(uint4*)(gBuf + ppos * GP + (ps << 4)) = o;
  }
  uint4 pTL, pTR, pBL, pBR;
  {  // pend = corners for chunk 1 (tap0, cg1)
    const int cbn = 32 + (ps << 3);
    const unsigned short* pT  = srcB + (size_t)(tabId & 0xFFFFu) * C + cbn;
    const unsigned short* pBm = srcB + (size_t)(tabId >> 16) * C + cbn;
    pTL = *(const uint4*)(pT);  pTR = *(const uint4*)(pT + C);
    pBL = *(const uint4*)(pBm); pBR = *(const uint4*)(pBm + C);
  }
  // A prefetch chunk 0 (direct global, L1-hot)
  short8 pa0_, pa1_;
  {
    const unsigned short* ap = wS + ((size_t)((2 * wv) * 64 + lane)) * 8;
    pa0_ = *(const short8*)(ap);
    pa1_ = *(const short8*)(ap + 512);
  }
  lgkm_barrier();

  #pragma unroll 2
  for (int ch = 0; ch < 36; ++ch) {
    const int p = ch & 1;
    const short8 af0 = pa0_, af1 = pa1_;
    if (ch + 1 < NCH3) {                       // A prefetch next chunk
      const unsigned short* ap = wS + ((size_t)((ch + 1) * 4096)) +
                                 ((size_t)((2 * wv) * 64 + lane)) * 8;
      pa0_ = *(const short8*)(ap);
      pa1_ = *(const short8*)(ap + 512);
    }
    // tab entry for chunk ch+2's tap
    unsigned ntId = tabId, ntW0 = tabW0, ntW1 = tabW1;
    if ((((ch + 2) & 3) == 0) && (ch + 2 < 36)) {
      const int tb = (((ch + 2) >> 2) * 64 + ppos) * 3;
      ntId = sTabU[tb]; ntW0 = sTabU[tb + 1]; ntW1 = sTabU[tb + 2];
    }
    // producer: issue corner loads for chunk ch+2
    uint4 nTL = pTL, nTR = pTR, nBL = pBL, nBR = pBR;
    if (ch + 2 < 36) {
      const int cbn = (((ch + 2) & 3) << 5) + (ps << 3);
      const unsigned short* pT  = srcB + (size_t)(ntId & 0xFFFFu) * C + cbn;
      const unsigned short* pBm = srcB + (size_t)(ntId >> 16) * C + cbn;
      nTL = *(const uint4*)(pT);  nTR = *(const uint4*)(pT + C);
      nBL = *(const uint4*)(pBm); nBR = *(const uint4*)(pBm + C);
    }
    // producer: blend pend (chunk ch+1) -> write gBuf[!p]
    if (ch + 1 < 36) {
      const float2 wa = h2f2(tabW0), wb = h2f2(tabW1);
      uint4 o;
      o.x = blend4(pTL.x, pTR.x, pBL.x, pBR.x, wa.x, wa.y, wb.x, wb.y);
      o.y = blend4(pTL.y, pTR.y, pBL.y, pBR.y, wa.x, wa.y, wb.x, wb.y);
      o.z = blend4(pTL.z, pTR.z, pBL.z, pBR.z, wa.x, wa.y, wb.x, wb.y);
      o.w = blend4(pTL.w, pTR.w, pBL.w, pBR.w, wa.x, wa.y, wb.x, wb.y);
      *(uint4*)(gBuf + (p ^ 1) * GHALF + ppos * GP + (ps << 4)) = o;
    }
    // consumer: 4 B-frags + 8 MFMA
    const char* gb = gBuf + p * GHALF;
    short8 bf[4];
    #pragma unroll
    for (int pg = 0; pg < 4; ++pg)
      bf[pg] = *(const short8*)(gb + (pg * 16 + m16) * GP + (q << 4));
    #pragma unroll
    for (int pg = 0; pg < 4; ++pg) {
      acc[0][pg] = __builtin_amdgcn_mfma_f32_16x16x32_bf16(af0, bf[pg], acc[0][pg], 0, 0, 0);
      acc[1][pg] = __builtin_amdgcn_mfma_f32_16x16x32_bf16(af1, bf[pg], acc[1][pg], 0, 0, 0);
    }
    // rotate pipeline
    pTL = nTL; pTR = nTR; pBL = nBL; pBR = nBR;
    tabId = ntId; tabW0 = ntW0; tabW1 = ntW1;
    if (ch + 1 < 36) lgkm_barrier();
  }

  if constexpr (BN) {   // chunk 36: BN-shift column; B = per-tap sums (sTab)
    const short8 af0 = pa0_, af1 = pa1_;       // prefetched wS[36]
    #pragma unroll
    for (int pg = 0; pg < 4; ++pg) {
      float sv[8];
      #pragma unroll
      for (int j = 0; j < 8; ++j) {
        const int k = (q << 3) + j;
        float s = 0.f;
        if (k < KK) {
          const int tb = (k * 64 + pg * 16 + m16) * 3;
          const float2 a = h2f2(sTabU[tb + 1]);
          const float2 c = h2f2(sTabU[tb + 2]);
          s = a.x + a.y + c.x + c.y;
        }
        sv[j] = s;
      }
      union { unsigned u[4]; short8 s; } bfr;
      #pragma unroll
      for (int t = 0; t < 4; ++t) bfr.u[t] = pack2bf(sv[2 * t], sv[2 * t + 1]);
      acc[0][pg] = __builtin_amdgcn_mfma_f32_16x16x32_bf16(af0, bfr.s, acc[0][pg], 0, 0, 0);
      acc[1][pg] = __builtin_amdgcn_mfma_f32_16x16x32_bf16(af1, bfr.s, acc[1][pg], 0, 0, 0);
    }
  }

  // ---- epilogue ----
  #pragma unroll
  for (int oi = 0; oi < 2; ++oi) {
    const int ot = wv * 2 + oi;
    if constexpr (LAYER == 1) {
      const float a0 = pA[ot * 16 + (q << 2) + 0];
      const float a1 = pA[ot * 16 + (q << 2) + 1];
      const float a2 = pA[ot * 16 + (q << 2) + 2];
      const float a3 = pA[ot * 16 + (q << 2) + 3];
      #pragma unroll
      for (int pg = 0; pg < 4; ++pg) {
        const float v0 = acc[oi][pg][0], v1 = acc[oi][pg][1];
        const float v2 = acc[oi][pg][2], v3 = acc[oi][pg][3];
        uint2 st;
        st.x = pack2bf(v0 > 0.f ? v0 : a0 * v0, v1 > 0.f ? v1 : a1 * v1);
        st.y = pack2bf(v2 > 0.f ? v2 : a2 * v2, v3 > 0.f ? v3 : a3 * v3);
        const int n = (b << 14) + hy * W + hx0 + pg * 16 + m16;
        *(uint2*)(outh + (size_t)n * C + ot * 16 + (q << 2)) = st;
      }
    } else {
      #pragma unroll
      for (int rg = 0; rg < 4; ++rg) {
        const int o = ot * 16 + (q << 2) + rg;
        const float s  = pA[o] * rsqrtf(pV[o] + 1e-5f);
        const float sh = pB[o] - pM[o] * s;
        #pragma unroll
        for (int pg = 0; pg < 4; ++pg) {
          const size_t oi2 = (((size_t)(b * C + o)) << 14) + hy * W + hx0 + pg * 16 + m16;
          outf[oi2] = acc[oi][pg][rg] * s + sh + resid[oi2];
        }
      }
    }
  }
}

// NCHW fp32 -> NHWC bf16, LDS-tiled (coalesced loads AND stores)
__global__ __launch_bounds__(256, 4)
void xcvt3(const float* __restrict__ x, unsigned short* __restrict__ xb)
{
  __shared__ unsigned tile[64 * 69];
  const int b   = blockIdx.y;
  const int p0  = blockIdx.x * 64;
  const int tid = threadIdx.x;
  const int pl  = tid & 63;
  const int cg  = tid >> 6;
  const float* __restrict__ xp = x + (((size_t)(b * C) + cg * 32) << 14) + p0 + pl;
  #pragma unroll
  for (int j = 0; j < 16; ++j) {
    const float a = xp[(size_t)(2 * j) << 14];
    const float c = xp[(size_t)(2 * j + 1) << 14];
    tile[pl * 69 + cg * 16 + j] = pack2bf(a, c);
  }
  __syncthreads();
  const int pl2 = tid >> 2;
  const int cq  = tid & 3;
  unsigned* dst = (unsigned*)(xb + (((size_t)(b << 14)) + p0 + pl2) * C + cq * 32);
  #pragma unroll
  for (int k = 0; k < 16; k += 4) {
    uint4 v;
    v.x = tile[pl2 * 69 + cq * 16 + k];
    v.y = tile[pl2 * 69 + cq * 16 + k + 1];
    v.z = tile[pl2 * 69 + cq * 16 + k + 2];
    v.w = tile[pl2 * 69 + cq * 16 + k + 3];
    *(uint4*)(dst + k) = v;
  }
}

// Swizzled weights, tap-major chunks: wS[((ch*NT+ot)*64+lane)*8+j] =
// w[o=ot*16+(lane&15)][c=(ch&3)*32+(lane>>4)*8+j][tap=ch>>2] (ch<36);
// ch==36: BN-shift col (kj=(lane>>4)*8+j < 9), layer-1 only.
__global__ void prep5(const float* __restrict__ w1, const float* __restrict__ w2,
                      const float* __restrict__ ow1, const float* __restrict__ mw1,
                      const float* __restrict__ ob1, const float* __restrict__ mb1,
                      const float* __restrict__ ow2, const float* __restrict__ mw2,
                      const float* __restrict__ ob2, const float* __restrict__ mb2,
                      const float* __restrict__ g, const float* __restrict__ bb,
                      const float* __restrict__ m, const float* __restrict__ v,
                      unsigned short* __restrict__ wb1, unsigned short* __restrict__ wb2,
                      unsigned short* __restrict__ wom1, unsigned short* __restrict__ wom2,
                      float* __restrict__ bias1, float* __restrict__ bias2)
{
  const int i = blockIdx.x * 256 + threadIdx.x;
  if (i < 128 * KT2) {              // deform, NT=8
    const int j = i & 7, lane = (i >> 3) & 63, ot = (i >> 9) & 7, ch = i >> 12;
    const int o = ot * 16 + (lane & 15);
    const int qj = ((lane >> 4) << 3) + j;
    unsigned short v1 = 0, v2 = 0;
    if (ch < 36) {
      const int tap = ch >> 2;
      const int c   = ((ch & 3) << 5) + qj;
      const float s = g[c] * rsqrtf(v[c] + 1e-5f);
      v1 = f2bf(w1[(size_t)(o * 128 + c) * 9 + tap] * s);
      v2 = f2bf(w2[(size_t)(o * 128 + c) * 9 + tap]);
    } else if (qj < KK) {
      float acc = 0.f;
      for (int c = 0; c < 128; ++c) {
        const float s  = g[c] * rsqrtf(v[c] + 1e-5f);
        const float sh = bb[c] - m[c] * s;
        acc += w1[(size_t)(o * 128 + c) * 9 + qj] * sh;
      }
      v1 = f2bf(acc);
    }
    wb1[i] = v1; wb2[i] = v2;
  }
  if (i < 32 * KT2) {               // offset/mask, NT=2
    const int j = i & 7, lane = (i >> 3) & 63, ot = (i >> 9) & 1, ch = i >> 10;
    const int o = ot * 16 + (lane & 15);
    const int qj = ((lane >> 4) << 3) + j;
    unsigned short v1 = 0, v2 = 0;
    if (ch < 36) {
      const int tap = ch >> 2;
      const int c   = ((ch & 3) << 5) + qj;
      const float s = g[c] * rsqrtf(v[c] + 1e-5f);
      if (o < 18) {
        v1 = f2bf(ow1[(size_t)(o * 128 + c) * 9 + tap] * s);
        v2 = f2bf(ow2[(size_t)(o * 128 + c) * 9 + tap]);
      } else if (o < 27) {
        v1 = f2bf(mw1[(size_t)((o - 18) * 128 + c) * 9 + tap] * s);
        v2 = f2bf(mw2[(size_t)((o - 18) * 128 + c) * 9 + tap]);
      }
    } else if (qj < KK && o < 27) {
      const float* wsrc = (o < 18) ? ow1 + (size_t)o * 1152
                                   : mw1 + (size_t)(o - 18) * 1152;
      float acc = 0.f;
      for (int c = 0; c < 128; ++c) {
        const float s  = g[c] * rsqrtf(v[c] + 1e-5f);
        const float sh = bb[c] - m[c] * s;
        acc += wsrc[(size_t)c * 9 + qj] * sh;
      }
      v1 = f2bf(acc);
    }
    wom1[i] = v1; wom2[i] = v2;
  }
  if (i < 32) {
    float b1 = 0.f, b2 = 0.f;
    if (i < 18)      { b1 = ob1[i];      b2 = ob2[i]; }
    else if (i < 27) { b1 = mb1[i - 18]; b2 = mb2[i - 18]; }
    bias1[i] = b1; bias2[i] = b2;
  }
}

extern "C" void kernel_launch(void* const* d_in, const int* in_sizes, int n_in,
                              void* d_out, int out_size, void* d_ws, size_t ws_size,
                              hipStream_t stream)
{
  const float* x     = (const float*)d_in[0];
  const float* bn1g  = (const float*)d_in[1];
  const float* bn1b  = (const float*)d_in[2];
  const float* bn1m  = (const float*)d_in[3];
  const float* bn1v  = (const float*)d_in[4];
  const float* ow1   = (const float*)d_in[5];
  const float* ob1   = (const float*)d_in[6];
  const float* mw1   = (const float*)d_in[7];
  const float* mb1   = (const float*)d_in[8];
  const float* w1    = (const float*)d_in[9];
  const float* alpha = (const float*)d_in[10];
  const float* ow2   = (const float*)d_in[11];
  const float* ob2   = (const float*)d_in[12];
  const float* mw2   = (const float*)d_in[13];
  const float* mb2   = (const float*)d_in[14];
  const float* w2    = (const float*)d_in[15];
  const float* bn2g  = (const float*)d_in[16];
  const float* bn2b  = (const float*)d_in[17];
  const float* bn2m  = (const float*)d_in[18];
  const float* bn2v  = (const float*)d_in[19];
  float* out = (float*)d_out;

  char* wsp = (char*)d_ws;
  unsigned short* xbf  = (unsigned short*)(wsp);             // NHWC bf16
  unsigned short* r2bf = (unsigned short*)(wsp + 16777216);  // NHWC bf16
  unsigned short* wb1  = (unsigned short*)(wsp + 40632320);  // 303104
  unsigned short* wb2  = (unsigned short*)(wsp + 40935424);  // 303104
  unsigned short* wom1 = (unsigned short*)(wsp + 41238528);  // 75776
  unsigned short* wom2 = (unsigned short*)(wsp + 41314304);  // 75776
  float* bias1 = (float*)(wsp + 41390080);
  float* bias2 = (float*)(wsp + 41390208);

  xcvt3<<<dim3(256, 4), 256, 0, stream>>>(x, xbf);
  prep5<<<(128 * KT2 + 255) / 256, 256, 0, stream>>>(
      w1, w2, ow1, mw1, ob1, mb1, ow2, mw2, ob2, mb2,
      bn1g, bn1b, bn1m, bn1v, wb1, wb2, wom1, wom2, bias1, bias2);

  fusedL<1><<<1024, 256, 0, stream>>>(xbf, wom1, wb1, bias1, alpha,
      nullptr, nullptr, nullptr, nullptr, r2bf, nullptr);
  fusedL<2><<<1024, 256, 0, stream>>>(r2bf, wom2, wb2, bias2, bn2g,
      bn2b, bn2m, bn2v, x, nullptr, out);
}